// Round 9
// baseline (2722.447 us; speedup 1.0000x reference)
//
#include <hip/hip_runtime.h>
#include <hip/hip_bf16.h>
#include <math.h>
#include <string.h>

#define L_TOK 16384
#define D_INP 256
#define D_MOD 768
#define D_FF  1536
#define N_LAYER 8
#define S_T 16
#define S_G 1024
#define EPSV 1e-5f

typedef short bf16x8 __attribute__((ext_vector_type(8)));
typedef float f32x4 __attribute__((ext_vector_type(4)));
typedef __hip_bfloat16 bf16;
typedef unsigned int u32;
typedef unsigned short u16;

__device__ __forceinline__ float fsigmoid(float z) { return 1.0f / (1.0f + __expf(-z)); }

__device__ __forceinline__ u16 f2bf(float f) {
  __hip_bfloat16 h = __float2bfloat16(f);
  u16 r; memcpy(&r, &h, 2); return r;
}
__device__ __forceinline__ float bf2f(u16 v) {
  u32 x = ((u32)v) << 16; float f; memcpy(&f, &x, 4); return f;
}

// async global->LDS, 16B per lane. LDS dest = (wave-uniform base) + lane*16.
__device__ __forceinline__ void glds16(const short* g, short* l) {
  __builtin_amdgcn_global_load_lds(
      (const __attribute__((address_space(1))) unsigned int*)(g),
      (__attribute__((address_space(3))) unsigned int*)(l), 16, 0, 0);
}

// inline-asm ds_read_b128, opaque to the compiler's waitcnt pass (round-3 lesson:
// compiler-visible LDS reads force a conservative vmcnt(0) drain against outstanding
// global_load_lds). Completion enforced manually: s_waitcnt lgkmcnt(0) +
// sched_barrier(0) (rule 18) before the MFMA cluster.
__device__ __forceinline__ bf16x8 dsr128(const char* base, int imm) {
  bf16x8 r;
  const __attribute__((address_space(3))) char* p =
      (const __attribute__((address_space(3))) char*)base;
  asm volatile("ds_read_b128 %0, %1 offset:%c2" : "=v"(r) : "v"(p), "i"(imm));
  return r;
}

// ---------------- f32 -> bf16, vectorized ----------------
__global__ void k_f32_to_bf16v(const float4* __restrict__ src, ushort4* __restrict__ dst, int n4) {
  int i = blockIdx.x * blockDim.x + threadIdx.x;
  if (i < n4) {
    float4 v = src[i];
    ushort4 o; o.x = f2bf(v.x); o.y = f2bf(v.y); o.z = f2bf(v.z); o.w = f2bf(v.w);
    dst[i] = o;
  }
}

// ------- transpose+convert (+optional LN-fold): src [z][R,C] f32 -> dst [z][C,R] bf16
template<bool FOLD>
__global__ void k_transpose_fold(const float* __restrict__ src, bf16* __restrict__ dst,
                                 int R, int C, size_t sstride, size_t dstride,
                                 const float* __restrict__ gv, const float* __restrict__ bv,
                                 float* __restrict__ wacc, float* __restrict__ bacc,
                                 int vstride) {
  __shared__ float tile[32][33];
  int z = blockIdx.z;
  const float* s = src + (size_t)z * sstride;
  bf16* d = dst + (size_t)z * dstride;
  int r0 = blockIdx.y * 32, c0 = blockIdx.x * 32;
  int tx = threadIdx.x, ty = threadIdx.y;
#pragma unroll
  for (int i = ty; i < 32; i += 8)
    tile[i][tx] = s[(size_t)(r0 + i) * C + (c0 + tx)];
  __syncthreads();
  float gk = 1.0f;
  if (FOLD) gk = gv[(size_t)z * R + r0 + tx];
#pragma unroll
  for (int i = ty; i < 32; i += 8) {
    float val = tile[tx][i];
    if (FOLD) val *= gk;
    d[(size_t)(c0 + i) * R + (r0 + tx)] = __float2bfloat16(val);
  }
  if (FOLD && ty == 0) {
    const float* gz = gv + (size_t)z * R + r0;
    const float* bz = bv + (size_t)z * R + r0;
    float s1 = 0.f, s2 = 0.f;
#pragma unroll 8
    for (int j = 0; j < 32; j++) {
      float wv = tile[j][tx];
      s1 += gz[j] * wv;
      s2 += bz[j] * wv;
    }
    atomicAdd(&wacc[(size_t)z * vstride + c0 + tx], s1);
    atomicAdd(&bacc[(size_t)z * vstride + c0 + tx], s2);
  }
}

// ---------------- bf16 MFMA GEMM: 128x128 tile, BK=32, 3 blocks/CU (TLP overlap) ----
// Round-5 proven form (67.7us @ N=1536): 3 LDS buffers, counted vmcnt(4) depth-2
// prefetch (never 0 mid-loop), asm ds_reads + single lgkmcnt(0)+sched_barrier(0).
// MODE: 0 bias; 2 silu; 3 bias+residual(bf16,in-place); 4 split u|gate.
// LNFOLD: A is raw residual x; val = rv*acc - rv*mu*wvec[gn] + bvec[gn] + bias.
// STATS: per-row sum/sumsq of written bf16 into stats_out (pre-zeroed).
template<int MODE, bool LNFOLD, bool STATS>
__global__ __launch_bounds__(256, 4) void k_gemm128(
    const short* __restrict__ A, const short* __restrict__ Bt,
    const float* __restrict__ bias, const float* __restrict__ bias2,
    const float* __restrict__ wvec, const float* __restrict__ bvec,
    const float* __restrict__ stats_in, float* __restrict__ stats_out,
    u16* __restrict__ res, u16* __restrict__ outp, u16* __restrict__ outp2,
    int N, int K, int ncol)
{
  __shared__ short As[3][128 * 32];
  __shared__ short Bs[3][128 * 32];
  __shared__ float s_mu[128], s_rv[128];
  const int tid = threadIdx.x;
  const int lane = tid & 63, w = tid >> 6;
  const int wr = w >> 1, wc = w & 1;
  const int l16 = lane & 15, qd = lane >> 4;

  const int b = blockIdx.x;
  const int xcd = b & 7, t = b >> 3;
  const int m0 = (xcd * 16 + t / ncol) * 128;
  const int n0 = (t % ncol) * 128;

  const int sr = lane >> 2, sc = lane & 3;
  const int ar = w * 32 + sr;
  const int acx = sc ^ ((ar >> 1) & 3);
  const short* ag0 = A  + (size_t)(m0 + ar) * K + acx * 8;
  const short* ag1 = ag0 + (size_t)16 * K;
  const short* bg0 = Bt + (size_t)(n0 + ar) * K + acx * 8;
  const short* bg1 = bg0 + (size_t)16 * K;

  auto stg = [&](int bi, int k0) {
    short* a0 = &As[bi][w * 1024];
    glds16(ag0 + k0, a0); glds16(ag1 + k0, a0 + 512);
    short* b0 = &Bs[bi][w * 1024];
    glds16(bg0 + k0, b0); glds16(bg1 + k0, b0 + 512);
  };

  const int fo = (qd ^ ((l16 >> 1) & 3)) * 8 + l16 * 32;

  // LN stats load issued first (oldest VMEM; waits stay counted, no queue drain)
  float sv = 0.f, sq = 0.f;
  if (LNFOLD && tid < 128) {
    sv = stats_in[2 * (m0 + tid)];
    sq = stats_in[2 * (m0 + tid) + 1];
  }

  const int NT = K >> 5;   // K is 256 or 768 -> NT >= 8
  // depth-2 prologue: tiles 0 and 1 (4 glds each per wave)
  stg(0, 0);
  stg(1, 32);

  if (LNFOLD && tid < 128) {
    float mu  = sv * (1.0f / (float)D_MOD);
    float var = sq * (1.0f / (float)D_MOD) - mu * mu;
    s_mu[tid] = mu;
    s_rv[tid] = 1.0f / sqrtf(var + EPSV);
  }

  f32x4 acc[4][4];
#pragma unroll
  for (int i = 0; i < 4; i++)
#pragma unroll
    for (int j = 0; j < 4; j++) acc[i][j] = (f32x4){0.f, 0.f, 0.f, 0.f};

  // tile 0 landed (our own oldest 4 glds; tile 1's 4 may stay in flight)
  asm volatile("s_waitcnt vmcnt(4)" ::: "memory");
  __builtin_amdgcn_s_barrier();

  int rd = 0;                       // rd = t % 3
  for (int t2 = 0; t2 < NT; ++t2) {
    const char* ab = (const char*)&As[rd][wr * 2048 + fo];
    const char* bb2 = (const char*)&Bs[rd][wc * 2048 + fo];
    bf16x8 af0 = dsr128(ab, 0),    af1 = dsr128(ab, 1024);
    bf16x8 af2 = dsr128(ab, 2048), af3 = dsr128(ab, 3072);
    bf16x8 bf0 = dsr128(bb2, 0),    bf1 = dsr128(bb2, 1024);
    bf16x8 bf2 = dsr128(bb2, 2048), bf3 = dsr128(bb2, 3072);
    if (t2 + 2 < NT) {
      int st = (rd == 0) ? 2 : rd - 1;   // (t+2) % 3 == buffer tile t-1 vacated
      stg(st, (t2 + 2) * 32);
    }
    asm volatile("s_waitcnt lgkmcnt(0)" ::: "memory");
    __builtin_amdgcn_sched_barrier(0);
    bf16x8 af[4] = {af0, af1, af2, af3};
    bf16x8 bfr[4] = {bf0, bf1, bf2, bf3};
#pragma unroll
    for (int rt = 0; rt < 4; rt++)
#pragma unroll
      for (int ct = 0; ct < 4; ct++)
        acc[rt][ct] = __builtin_amdgcn_mfma_f32_16x16x32_bf16(af[rt], bfr[ct], acc[rt][ct], 0, 0, 0);
    // tile t+1 must be fully landed before next iter reads it; keep t+2 in flight
    if (t2 + 2 < NT) asm volatile("s_waitcnt vmcnt(4)" ::: "memory");
    else             asm volatile("s_waitcnt vmcnt(0)" ::: "memory");
    __builtin_amdgcn_s_barrier();
    rd = (rd == 2) ? 0 : rd + 1;
  }

  // ---- epilogue. C/D map col=lane&15, row=(lane>>4)*4+reg ----
  const float* bb = bias;
  u16* op = outp;
  int nofs = 0, Nout = N;
  bool sig = false;
  if (MODE == 4) {
    Nout = N >> 1;
    if (n0 >= Nout) { bb = bias2; op = outp2; nofs = Nout; sig = true; }
  }
  const int gmb = m0 + wr * 64 + qd * 4;
  const int gnb = n0 + wc * 64 + l16;
  float bc[4], wv4[4], bv4[4];
#pragma unroll
  for (int ct = 0; ct < 4; ct++) {
    int gn = gnb + ct * 16;
    bc[ct] = bb[gn - nofs];
    if (LNFOLD) { wv4[ct] = wvec[gn]; bv4[ct] = bvec[gn]; }
  }
#pragma unroll
  for (int rt = 0; rt < 4; rt++) {
#pragma unroll
    for (int r = 0; r < 4; r++) {
      const int gm = gmb + rt * 16 + r;
      float mu = 0.f, rv = 0.f;
      if (LNFOLD) { mu = s_mu[gm - m0]; rv = s_rv[gm - m0]; }
      float ps = 0.f, ps2 = 0.f;
#pragma unroll
      for (int ct = 0; ct < 4; ct++) {
        int gn = gnb + ct * 16;
        float vv = acc[rt][ct][r];
        if (LNFOLD) vv = rv * vv - rv * mu * wv4[ct] + bv4[ct] + bc[ct];
        else        vv += bc[ct];
        if (MODE == 2) vv = vv * fsigmoid(vv);
        if (MODE == 4 && sig) vv = fsigmoid(vv);
        size_t oidx = (size_t)gm * Nout + (gn - nofs);
        if (MODE == 3) vv += bf2f(res[oidx]);
        u16 rb = f2bf(vv);
        op[oidx] = rb;
        if (STATS) { float fv = bf2f(rb); ps += fv; ps2 += fv * fv; }
      }
      if (STATS) {
#pragma unroll
        for (int o = 1; o < 16; o <<= 1) {
          ps  += __shfl_xor(ps, o, 64);
          ps2 += __shfl_xor(ps2, o, 64);
        }
        if (l16 == 0) {
          atomicAdd(&stats_out[2 * gm], ps);
          atomicAdd(&stats_out[2 * gm + 1], ps2);
        }
      }
    }
  }
}

// ---------------- chunked linear-recurrence scan (u bf16, 4 ch/thread) ----------------
// S_T=16, S_G=1024: 4 blocks/CU (12 waves/CU) instead of 1 -- the round-6 counters
// showed the scans latency-bound at Occupancy 4.4% / 740 GB/s. Shorter chunks give
// 4x TLP; 1-deep explicit prefetch adds MLP within each wave.
__global__ void k_scan_a(const bf16* __restrict__ u, const float* __restrict__ dl,
                         float* __restrict__ clast) {
  int t = threadIdx.x;            // 0..191
  int g = blockIdx.x;
  int d0 = t * 4;
  float dec[4], s[4] = {0.f, 0.f, 0.f, 0.f};
#pragma unroll
  for (int c = 0; c < 4; c++) dec[c] = fsigmoid(dl[d0 + c]);
  const ushort4* up = (const ushort4*)(u + (size_t)g * S_T * D_MOD) + t;
  ushort4 nxt = up[0];
#pragma unroll 4
  for (int tt = 0; tt < S_T; tt++) {
    ushort4 uv = nxt;
    if (tt + 1 < S_T) nxt = up[(size_t)(tt + 1) * 192];
    s[0] = fmaf(dec[0], s[0], bf2f(uv.x));
    s[1] = fmaf(dec[1], s[1], bf2f(uv.y));
    s[2] = fmaf(dec[2], s[2], bf2f(uv.z));
    s[3] = fmaf(dec[3], s[3], bf2f(uv.w));
  }
#pragma unroll
  for (int c = 0; c < 4; c++) clast[(size_t)g * D_MOD + d0 + c] = s[c];
}

__global__ void k_scan_b(const float* __restrict__ clast, const float* __restrict__ dl,
                         float* __restrict__ carry) {
  int d = threadIdx.x;
  float decay = fsigmoid(dl[d]);
  float aT = decay;
#pragma unroll
  for (int i = 0; i < 4; i++) aT *= aT;   // decay^16
  float c = 0.f;
  for (int g = 0; g < S_G; g++) {
    carry[(size_t)g * D_MOD + d] = c;
    c = fmaf(aT, c, clast[(size_t)g * D_MOD + d]);
  }
}

__global__ void k_scan_c(const bf16* __restrict__ u, const float* __restrict__ dl,
                         const float* __restrict__ carry, bf16* __restrict__ gate_s) {
  int t = threadIdx.x;            // 0..191
  int g = blockIdx.x;
  int d0 = t * 4;
  float dec[4], s[4];
#pragma unroll
  for (int c = 0; c < 4; c++) {
    dec[c] = fsigmoid(dl[d0 + c]);
    s[c] = carry[(size_t)g * D_MOD + d0 + c];
  }
  const ushort4* up = (const ushort4*)(u + (size_t)g * S_T * D_MOD) + t;
  ushort4* gp = (ushort4*)(gate_s + (size_t)g * S_T * D_MOD) + t;
  ushort4 nu = up[0], ng = gp[0];
#pragma unroll 4
  for (int tt = 0; tt < S_T; tt++) {
    ushort4 uv = nu, gv = ng;
    if (tt + 1 < S_T) {
      nu = up[(size_t)(tt + 1) * 192];
      ng = gp[(size_t)(tt + 1) * 192];
    }
    s[0] = fmaf(dec[0], s[0], bf2f(uv.x));
    s[1] = fmaf(dec[1], s[1], bf2f(uv.y));
    s[2] = fmaf(dec[2], s[2], bf2f(uv.z));
    s[3] = fmaf(dec[3], s[3], bf2f(uv.w));
    ushort4 ov;
    ov.x = f2bf(s[0] * bf2f(gv.x));
    ov.y = f2bf(s[1] * bf2f(gv.y));
    ov.z = f2bf(s[2] * bf2f(gv.z));
    ov.w = f2bf(s[3] * bf2f(gv.w));
    gp[(size_t)tt * 192] = ov;
  }
}

// ---------------- final LN: x bf16 + precomputed stats -> f32 out ----------------
__global__ __launch_bounds__(256) void k_ln_final(const u16* __restrict__ x,
    const float* __restrict__ stats, const float* __restrict__ g,
    const float* __restrict__ b, float* __restrict__ outp) {
  int wv = threadIdx.x >> 6, lane = threadIdx.x & 63;
  int row = blockIdx.x * 4 + wv;
  float sv = stats[2 * row], sq = stats[2 * row + 1];
  float mu = sv * (1.0f / (float)D_MOD);
  float var = sq * (1.0f / (float)D_MOD) - mu * mu;
  float rv = 1.0f / sqrtf(var + EPSV);
  const ushort4* xr = (const ushort4*)(x + (size_t)row * D_MOD);
  const float4* g4 = (const float4*)g;
  const float4* b4 = (const float4*)b;
  float4* o4 = (float4*)(outp + (size_t)row * D_MOD);
#pragma unroll
  for (int j = 0; j < 3; j++) {
    int f = j * 64 + lane;
    ushort4 xv = xr[f];
    float4 gg = g4[f], bb = b4[f], ov;
    ov.x = (bf2f(xv.x) - mu) * rv * gg.x + bb.x;
    ov.y = (bf2f(xv.y) - mu) * rv * gg.y + bb.y;
    ov.z = (bf2f(xv.z) - mu) * rv * gg.z + bb.z;
    ov.w = (bf2f(xv.w) - mu) * rv * gg.w + bb.w;
    o4[f] = ov;
  }
}

extern "C" void kernel_launch(void* const* d_in, const int* in_sizes, int n_in,
                              void* d_out, int out_size, void* d_ws, size_t ws_size,
                              hipStream_t stream) {
  const float* nf     = (const float*)d_in[0];
  const float* W_proj = (const float*)d_in[1];
  const float* b_proj = (const float*)d_in[2];
  const float* ln_s_g = (const float*)d_in[3];
  const float* ln_s_b = (const float*)d_in[4];
  const float* W_in   = (const float*)d_in[5];
  const float* b_in   = (const float*)d_in[6];
  const float* W_gate = (const float*)d_in[7];
  const float* b_gate = (const float*)d_in[8];
  const float* W_out  = (const float*)d_in[9];
  const float* b_out  = (const float*)d_in[10];
  const float* dlogit = (const float*)d_in[11];
  const float* ln_f_g = (const float*)d_in[12];
  const float* ln_f_b = (const float*)d_in[13];
  const float* W_ff1  = (const float*)d_in[14];
  const float* b_ff1  = (const float*)d_in[15];
  const float* W_ff2  = (const float*)d_in[16];
  const float* b_ff2  = (const float*)d_in[17];
  const float* ln_o_g = (const float*)d_in[18];
  const float* ln_o_b = (const float*)d_in[19];
  (void)in_sizes; (void)n_in;

  char* ws = (char*)d_ws;
  size_t off = 0;
  auto alloc = [&](size_t bytes) -> char* {
    char* p = ws + off;
    off = (off + bytes + 255) & ~(size_t)255;
    return p;
  };
  const bool big = ws_size >= (160ull << 20);
  const size_t wmul = big ? N_LAYER : 1;

  u16*   x     = (u16*)alloc(2ull * L_TOK * D_MOD);        // residual stream, bf16 (25 MB)
  // shared region (50.3 MB): nfb (pre-loop) | u+gate (recurrence) | tb (FF)
  char*  ug    = alloc(2ull * L_TOK * D_FF);
  u16*   u     = (u16*)ug;
  u16*   gate  = (u16*)(ug + 2ull * L_TOK * D_MOD);
  u16*   tb    = (u16*)ug;
  u16*   nfb   = (u16*)ug;
  bf16*  WprojT= (bf16*)alloc(2ull * D_INP * D_MOD);
  bf16*  WigT  = (bf16*)alloc(2ull * wmul * (2 * D_MOD) * D_MOD);  // [g∘W_in^T ; g∘W_gate^T]
  bf16*  WoT   = (bf16*)alloc(2ull * wmul * D_MOD * D_MOD);
  bf16*  Wff1T = (bf16*)alloc(2ull * wmul * D_MOD * D_FF);
  bf16*  Wff2T = (bf16*)alloc(2ull * wmul * D_FF * D_MOD);
  float* clast = (float*)alloc(sizeof(float) * (size_t)S_G * D_MOD);
  float* carry = (float*)alloc(sizeof(float) * (size_t)S_G * D_MOD);
  // zeroed region: stats slots [17][16384][2] + fold vectors
  char*  zbase = alloc(0);
  float* stats = (float*)alloc(sizeof(float) * 17ull * L_TOK * 2);     // 2.23 MB
  float* wvig  = (float*)alloc(sizeof(float) * N_LAYER * 2 * D_MOD);   // g_s@[W_in|W_gate]
  float* bvig  = (float*)alloc(sizeof(float) * N_LAYER * 2 * D_MOD);
  float* wvf1  = (float*)alloc(sizeof(float) * N_LAYER * D_FF);        // g_f@W_ff1
  float* bvf1  = (float*)alloc(sizeof(float) * N_LAYER * D_FF);
  size_t zbytes = (size_t)((char*)ws + off - zbase);
  hipMemsetAsync(zbase, 0, zbytes, stream);

  const size_t DD = (size_t)D_MOD * D_MOD, DF = (size_t)D_MOD * D_FF;
  auto statslot = [&](int s) { return stats + (size_t)s * L_TOK * 2; };
  dim3 tb32(32, 8);
  k_f32_to_bf16v<<<(L_TOK * D_INP / 4 + 255) / 256, 256, 0, stream>>>(
      (const float4*)nf, (ushort4*)nfb, L_TOK * D_INP / 4);
  k_transpose_fold<false><<<dim3(D_MOD / 32, D_INP / 32, 1), tb32, 0, stream>>>(
      W_proj, WprojT, D_INP, D_MOD, 0, 0, nullptr, nullptr, nullptr, nullptr, 0);
  if (big) {
    k_transpose_fold<true><<<dim3(D_MOD / 32, D_MOD / 32, N_LAYER), tb32, 0, stream>>>(
        W_in,   WigT,      D_MOD, D_MOD, DD, 2 * DD, ln_s_g, ln_s_b, wvig,       bvig,       2 * D_MOD);
    k_transpose_fold<true><<<dim3(D_MOD / 32, D_MOD / 32, N_LAYER), tb32, 0, stream>>>(
        W_gate, WigT + DD, D_MOD, D_MOD, DD, 2 * DD, ln_s_g, ln_s_b, wvig + D_MOD, bvig + D_MOD, 2 * D_MOD);
    k_transpose_fold<false><<<dim3(D_MOD / 32, D_MOD / 32, N_LAYER), tb32, 0, stream>>>(
        W_out,  WoT,       D_MOD, D_MOD, DD, DD, nullptr, nullptr, nullptr, nullptr, 0);
    k_transpose_fold<true><<<dim3(D_FF / 32,  D_MOD / 32, N_LAYER), tb32, 0, stream>>>(
        W_ff1,  Wff1T,     D_MOD, D_FF,  DF, DF, ln_f_g, ln_f_b, wvf1, bvf1, D_FF);
    k_transpose_fold<false><<<dim3(D_MOD / 32, D_FF / 32,  N_LAYER), tb32, 0, stream>>>(
        W_ff2,  Wff2T,     D_FF,  D_MOD, DF, DF, nullptr, nullptr, nullptr, nullptr, 0);
  }

  // x = nf @ W_proj + b_proj  (bf16 out + stats slot 0)
  k_gemm128<0, false, true><<<128 * 6, 256, 0, stream>>>(
      (const short*)nfb, (const short*)WprojT, b_proj, nullptr, nullptr, nullptr,
      nullptr, statslot(0), nullptr, x, nullptr, D_MOD, D_INP, 6);

  for (int l = 0; l < N_LAYER; l++) {
    const bf16 *wigT, *woT, *wf1T, *wf2T;
    if (big) {
      wigT = WigT  + (size_t)l * 2 * DD;
      woT  = WoT   + (size_t)l * DD;
      wf1T = Wff1T + (size_t)l * DF;
      wf2T = Wff2T + (size_t)l * DF;
    } else {
      k_transpose_fold<true><<<dim3(D_MOD / 32, D_MOD / 32, 1), tb32, 0, stream>>>(
          W_in + (size_t)l * DD, WigT, D_MOD, D_MOD, 0, 0,
          ln_s_g + l * D_MOD, ln_s_b + l * D_MOD, wvig + (size_t)l * 2 * D_MOD, bvig + (size_t)l * 2 * D_MOD, 0);
      k_transpose_fold<true><<<dim3(D_MOD / 32, D_MOD / 32, 1), tb32, 0, stream>>>(
          W_gate + (size_t)l * DD, WigT + DD, D_MOD, D_MOD, 0, 0,
          ln_s_g + l * D_MOD, ln_s_b + l * D_MOD, wvig + (size_t)l * 2 * D_MOD + D_MOD, bvig + (size_t)l * 2 * D_MOD + D_MOD, 0);
      k_transpose_fold<false><<<dim3(D_MOD / 32, D_MOD / 32, 1), tb32, 0, stream>>>(
          W_out + (size_t)l * DD, WoT, D_MOD, D_MOD, 0, 0, nullptr, nullptr, nullptr, nullptr, 0);
      k_transpose_fold<true><<<dim3(D_FF / 32, D_MOD / 32, 1), tb32, 0, stream>>>(
          W_ff1 + (size_t)l * DF, Wff1T, D_MOD, D_FF, 0, 0,
          ln_f_g + l * D_MOD, ln_f_b + l * D_MOD, wvf1 + (size_t)l * D_FF, bvf1 + (size_t)l * D_FF, 0);
      k_transpose_fold<false><<<dim3(D_MOD / 32, D_FF / 32, 1), tb32, 0, stream>>>(
          W_ff2 + (size_t)l * DF, Wff2T, D_FF, D_MOD, 0, 0, nullptr, nullptr, nullptr, nullptr, 0);
      wigT = WigT; woT = WoT; wf1T = Wff1T; wf2T = Wff2T;
    }

    // fused LN_s + (u | gate) GEMM: A = x directly
    k_gemm128<4, true, false><<<128 * 12, 256, 0, stream>>>(
        (const short*)x, (const short*)wigT, b_in + l * D_MOD, b_gate + l * D_MOD,
        wvig + (size_t)l * 2 * D_MOD, bvig + (size_t)l * 2 * D_MOD,
        statslot(2 * l), nullptr, nullptr, u, gate, 2 * D_MOD, D_MOD, 12);
    // chunked scan; s*gate -> gate buffer (bf16)
    k_scan_a<<<S_G, 192, 0, stream>>>((const bf16*)u, dlogit + l * D_MOD, clast);
    k_scan_b<<<1, D_MOD, 0, stream>>>(clast, dlogit + l * D_MOD, carry);
    k_scan_c<<<S_G, 192, 0, stream>>>((const bf16*)u, dlogit + l * D_MOD, carry, (bf16*)gate);
    // x = x + sg @ W_out + b_out  (bf16 in-place + stats slot 2l+1)
    k_gemm128<3, false, true><<<128 * 6, 256, 0, stream>>>(
        (const short*)gate, (const short*)woT, b_out + l * D_MOD, nullptr, nullptr, nullptr,
        nullptr, statslot(2 * l + 1), x, x, nullptr, D_MOD, D_MOD, 6);
    // fused LN_f + FF1 (silu): A = x directly
    k_gemm128<2, true, false><<<128 * 12, 256, 0, stream>>>(
        (const short*)x, (const short*)wf1T, b_ff1 + l * D_FF, nullptr,
        wvf1 + (size_t)l * D_FF, bvf1 + (size_t)l * D_FF,
        statslot(2 * l + 1), nullptr, nullptr, tb, nullptr, D_FF, D_MOD, 12);
    // x = x + tb @ W_ff2 + b_ff2  (bf16 in-place + stats slot 2l+2)
    k_gemm128<3, false, true><<<128 * 6, 256, 0, stream>>>(
        (const short*)tb, (const short*)wf2T, b_ff2 + l * D_MOD, nullptr, nullptr, nullptr,
        nullptr, statslot(2 * l + 2), x, x, nullptr, D_MOD, D_FF, 6);
  }

  // out = LN_o(x) (f32) using stats slot 16
  k_ln_final<<<L_TOK / 4, 256, 0, stream>>>(x, statslot(2 * N_LAYER), ln_o_g, ln_o_b, (float*)d_out);
}

// Round 10
// 2177.702 us; speedup vs baseline: 1.2501x; 1.2501x over previous
//
#include <hip/hip_runtime.h>
#include <hip/hip_bf16.h>
#include <math.h>
#include <string.h>

#define L_TOK 16384
#define D_INP 256
#define D_MOD 768
#define D_FF  1536
#define N_LAYER 8
#define S_T 16
#define S_G 1024
#define S_SB 32
#define EPSV 1e-5f

typedef short bf16x8 __attribute__((ext_vector_type(8)));
typedef float f32x4 __attribute__((ext_vector_type(4)));
typedef __hip_bfloat16 bf16;
typedef unsigned int u32;
typedef unsigned short u16;

__device__ __forceinline__ float fsigmoid(float z) { return 1.0f / (1.0f + __expf(-z)); }

__device__ __forceinline__ u16 f2bf(float f) {
  __hip_bfloat16 h = __float2bfloat16(f);
  u16 r; memcpy(&r, &h, 2); return r;
}
__device__ __forceinline__ float bf2f(u16 v) {
  u32 x = ((u32)v) << 16; float f; memcpy(&f, &x, 4); return f;
}

// async global->LDS, 16B per lane. LDS dest = (wave-uniform base) + lane*16.
__device__ __forceinline__ void glds16(const short* g, short* l) {
  __builtin_amdgcn_global_load_lds(
      (const __attribute__((address_space(1))) unsigned int*)(g),
      (__attribute__((address_space(3))) unsigned int*)(l), 16, 0, 0);
}

// inline-asm ds_read_b128, opaque to the compiler's waitcnt pass (round-3 lesson:
// compiler-visible LDS reads force a conservative vmcnt(0) drain against outstanding
// global_load_lds). Completion enforced manually: s_waitcnt lgkmcnt(0) +
// sched_barrier(0) (rule 18) before the MFMA cluster.
__device__ __forceinline__ bf16x8 dsr128(const char* base, int imm) {
  bf16x8 r;
  const __attribute__((address_space(3))) char* p =
      (const __attribute__((address_space(3))) char*)base;
  asm volatile("ds_read_b128 %0, %1 offset:%c2" : "=v"(r) : "v"(p), "i"(imm));
  return r;
}

// ---------------- f32 -> bf16, vectorized ----------------
__global__ void k_f32_to_bf16v(const float4* __restrict__ src, ushort4* __restrict__ dst, int n4) {
  int i = blockIdx.x * blockDim.x + threadIdx.x;
  if (i < n4) {
    float4 v = src[i];
    ushort4 o; o.x = f2bf(v.x); o.y = f2bf(v.y); o.z = f2bf(v.z); o.w = f2bf(v.w);
    dst[i] = o;
  }
}

// ------- transpose+convert (+optional LN-fold): src [z][R,C] f32 -> dst [z][C,R] bf16
template<bool FOLD>
__global__ void k_transpose_fold(const float* __restrict__ src, bf16* __restrict__ dst,
                                 int R, int C, size_t sstride, size_t dstride,
                                 const float* __restrict__ gv, const float* __restrict__ bv,
                                 float* __restrict__ wacc, float* __restrict__ bacc,
                                 int vstride) {
  __shared__ float tile[32][33];
  int z = blockIdx.z;
  const float* s = src + (size_t)z * sstride;
  bf16* d = dst + (size_t)z * dstride;
  int r0 = blockIdx.y * 32, c0 = blockIdx.x * 32;
  int tx = threadIdx.x, ty = threadIdx.y;
#pragma unroll
  for (int i = ty; i < 32; i += 8)
    tile[i][tx] = s[(size_t)(r0 + i) * C + (c0 + tx)];
  __syncthreads();
  float gk = 1.0f;
  if (FOLD) gk = gv[(size_t)z * R + r0 + tx];
#pragma unroll
  for (int i = ty; i < 32; i += 8) {
    float val = tile[tx][i];
    if (FOLD) val *= gk;
    d[(size_t)(c0 + i) * R + (r0 + tx)] = __float2bfloat16(val);
  }
  if (FOLD && ty == 0) {
    const float* gz = gv + (size_t)z * R + r0;
    const float* bz = bv + (size_t)z * R + r0;
    float s1 = 0.f, s2 = 0.f;
#pragma unroll 8
    for (int j = 0; j < 32; j++) {
      float wv = tile[j][tx];
      s1 += gz[j] * wv;
      s2 += bz[j] * wv;
    }
    atomicAdd(&wacc[(size_t)z * vstride + c0 + tx], s1);
    atomicAdd(&bacc[(size_t)z * vstride + c0 + tx], s2);
  }
}

// ---------------- bf16 MFMA GEMM: 128x128 tile, BK=32, 3 blocks/CU (TLP overlap) ----
// Round-5 proven form (67.7us @ N=1536): 3 LDS buffers, counted vmcnt(4) depth-2
// prefetch (never 0 mid-loop), asm ds_reads + single lgkmcnt(0)+sched_barrier(0).
// MODE: 0 bias; 2 silu; 3 bias+residual(bf16,in-place); 4 split u|gate.
// LNFOLD: A is raw residual x; val = rv*acc - rv*mu*wvec[gn] + bvec[gn] + bias.
// STATS: per-row sum/sumsq of written bf16 into stats_out (pre-zeroed).
template<int MODE, bool LNFOLD, bool STATS>
__global__ __launch_bounds__(256, 4) void k_gemm128(
    const short* __restrict__ A, const short* __restrict__ Bt,
    const float* __restrict__ bias, const float* __restrict__ bias2,
    const float* __restrict__ wvec, const float* __restrict__ bvec,
    const float* __restrict__ stats_in, float* __restrict__ stats_out,
    u16* __restrict__ res, u16* __restrict__ outp, u16* __restrict__ outp2,
    int N, int K, int ncol)
{
  __shared__ short As[3][128 * 32];
  __shared__ short Bs[3][128 * 32];
  __shared__ float s_mu[128], s_rv[128];
  const int tid = threadIdx.x;
  const int lane = tid & 63, w = tid >> 6;
  const int wr = w >> 1, wc = w & 1;
  const int l16 = lane & 15, qd = lane >> 4;

  const int b = blockIdx.x;
  const int xcd = b & 7, t = b >> 3;
  const int m0 = (xcd * 16 + t / ncol) * 128;
  const int n0 = (t % ncol) * 128;

  const int sr = lane >> 2, sc = lane & 3;
  const int ar = w * 32 + sr;
  const int acx = sc ^ ((ar >> 1) & 3);
  const short* ag0 = A  + (size_t)(m0 + ar) * K + acx * 8;
  const short* ag1 = ag0 + (size_t)16 * K;
  const short* bg0 = Bt + (size_t)(n0 + ar) * K + acx * 8;
  const short* bg1 = bg0 + (size_t)16 * K;

  auto stg = [&](int bi, int k0) {
    short* a0 = &As[bi][w * 1024];
    glds16(ag0 + k0, a0); glds16(ag1 + k0, a0 + 512);
    short* b0 = &Bs[bi][w * 1024];
    glds16(bg0 + k0, b0); glds16(bg1 + k0, b0 + 512);
  };

  const int fo = (qd ^ ((l16 >> 1) & 3)) * 8 + l16 * 32;

  // LN stats load issued first (oldest VMEM; waits stay counted, no queue drain)
  float sv = 0.f, sq = 0.f;
  if (LNFOLD && tid < 128) {
    sv = stats_in[2 * (m0 + tid)];
    sq = stats_in[2 * (m0 + tid) + 1];
  }

  const int NT = K >> 5;   // K is 256 or 768 -> NT >= 8
  // depth-2 prologue: tiles 0 and 1 (4 glds each per wave)
  stg(0, 0);
  stg(1, 32);

  if (LNFOLD && tid < 128) {
    float mu  = sv * (1.0f / (float)D_MOD);
    float var = sq * (1.0f / (float)D_MOD) - mu * mu;
    s_mu[tid] = mu;
    s_rv[tid] = 1.0f / sqrtf(var + EPSV);
  }

  f32x4 acc[4][4];
#pragma unroll
  for (int i = 0; i < 4; i++)
#pragma unroll
    for (int j = 0; j < 4; j++) acc[i][j] = (f32x4){0.f, 0.f, 0.f, 0.f};

  // tile 0 landed (our own oldest 4 glds; tile 1's 4 may stay in flight)
  asm volatile("s_waitcnt vmcnt(4)" ::: "memory");
  __builtin_amdgcn_s_barrier();

  int rd = 0;                       // rd = t % 3
  for (int t2 = 0; t2 < NT; ++t2) {
    const char* ab = (const char*)&As[rd][wr * 2048 + fo];
    const char* bb2 = (const char*)&Bs[rd][wc * 2048 + fo];
    bf16x8 af0 = dsr128(ab, 0),    af1 = dsr128(ab, 1024);
    bf16x8 af2 = dsr128(ab, 2048), af3 = dsr128(ab, 3072);
    bf16x8 bf0 = dsr128(bb2, 0),    bf1 = dsr128(bb2, 1024);
    bf16x8 bf2 = dsr128(bb2, 2048), bf3 = dsr128(bb2, 3072);
    if (t2 + 2 < NT) {
      int st = (rd == 0) ? 2 : rd - 1;   // (t+2) % 3 == buffer tile t-1 vacated
      stg(st, (t2 + 2) * 32);
    }
    asm volatile("s_waitcnt lgkmcnt(0)" ::: "memory");
    __builtin_amdgcn_sched_barrier(0);
    bf16x8 af[4] = {af0, af1, af2, af3};
    bf16x8 bfr[4] = {bf0, bf1, bf2, bf3};
#pragma unroll
    for (int rt = 0; rt < 4; rt++)
#pragma unroll
      for (int ct = 0; ct < 4; ct++)
        acc[rt][ct] = __builtin_amdgcn_mfma_f32_16x16x32_bf16(af[rt], bfr[ct], acc[rt][ct], 0, 0, 0);
    // tile t+1 must be fully landed before next iter reads it; keep t+2 in flight
    if (t2 + 2 < NT) asm volatile("s_waitcnt vmcnt(4)" ::: "memory");
    else             asm volatile("s_waitcnt vmcnt(0)" ::: "memory");
    __builtin_amdgcn_s_barrier();
    rd = (rd == 2) ? 0 : rd + 1;
  }

  // ---- epilogue. C/D map col=lane&15, row=(lane>>4)*4+reg ----
  const float* bb = bias;
  u16* op = outp;
  int nofs = 0, Nout = N;
  bool sig = false;
  if (MODE == 4) {
    Nout = N >> 1;
    if (n0 >= Nout) { bb = bias2; op = outp2; nofs = Nout; sig = true; }
  }
  const int gmb = m0 + wr * 64 + qd * 4;
  const int gnb = n0 + wc * 64 + l16;
  float bc[4], wv4[4], bv4[4];
#pragma unroll
  for (int ct = 0; ct < 4; ct++) {
    int gn = gnb + ct * 16;
    bc[ct] = bb[gn - nofs];
    if (LNFOLD) { wv4[ct] = wvec[gn]; bv4[ct] = bvec[gn]; }
  }
#pragma unroll
  for (int rt = 0; rt < 4; rt++) {
#pragma unroll
    for (int r = 0; r < 4; r++) {
      const int gm = gmb + rt * 16 + r;
      float mu = 0.f, rv = 0.f;
      if (LNFOLD) { mu = s_mu[gm - m0]; rv = s_rv[gm - m0]; }
      float ps = 0.f, ps2 = 0.f;
#pragma unroll
      for (int ct = 0; ct < 4; ct++) {
        int gn = gnb + ct * 16;
        float vv = acc[rt][ct][r];
        if (LNFOLD) vv = rv * vv - rv * mu * wv4[ct] + bv4[ct] + bc[ct];
        else        vv += bc[ct];
        if (MODE == 2) vv = vv * fsigmoid(vv);
        if (MODE == 4 && sig) vv = fsigmoid(vv);
        size_t oidx = (size_t)gm * Nout + (gn - nofs);
        if (MODE == 3) vv += bf2f(res[oidx]);
        u16 rb = f2bf(vv);
        op[oidx] = rb;
        if (STATS) { float fv = bf2f(rb); ps += fv; ps2 += fv * fv; }
      }
      if (STATS) {
#pragma unroll
        for (int o = 1; o < 16; o <<= 1) {
          ps  += __shfl_xor(ps, o, 64);
          ps2 += __shfl_xor(ps2, o, 64);
        }
        if (l16 == 0) {
          atomicAdd(&stats_out[2 * gm], ps);
          atomicAdd(&stats_out[2 * gm + 1], ps2);
        }
      }
    }
  }
}

// ---------------- chunked linear-recurrence scan (u bf16, 4 ch/thread) ----------------
// S_T=16, S_G=1024 (4 blocks/CU TLP for a/c). The group-level scan (1024 groups) is
// now HIERARCHICAL: round-9 counters showed the flat 1-block scan_b at 76.7us
// (1024 serial L2-latency fmas, 255 CUs idle). b1: 32 blocks each scan 32 groups
// (zero-entry inner carries + superblock total, loads batch-issued by full unroll);
// b2: 1 block scans 32 superblocks (decay^512 multiplier); c applies
// carry[g] = inner[g] + aTg^(g&31) * sbcarry[g>>5] in-register (block-uniform e).
__global__ void k_scan_a(const bf16* __restrict__ u, const float* __restrict__ dl,
                         float* __restrict__ clast) {
  int t = threadIdx.x;            // 0..191
  int g = blockIdx.x;
  int d0 = t * 4;
  float dec[4], s[4] = {0.f, 0.f, 0.f, 0.f};
#pragma unroll
  for (int c = 0; c < 4; c++) dec[c] = fsigmoid(dl[d0 + c]);
  const ushort4* up = (const ushort4*)(u + (size_t)g * S_T * D_MOD) + t;
  ushort4 nxt = up[0];
#pragma unroll 4
  for (int tt = 0; tt < S_T; tt++) {
    ushort4 uv = nxt;
    if (tt + 1 < S_T) nxt = up[(size_t)(tt + 1) * 192];
    s[0] = fmaf(dec[0], s[0], bf2f(uv.x));
    s[1] = fmaf(dec[1], s[1], bf2f(uv.y));
    s[2] = fmaf(dec[2], s[2], bf2f(uv.z));
    s[3] = fmaf(dec[3], s[3], bf2f(uv.w));
  }
#pragma unroll
  for (int c = 0; c < 4; c++) clast[(size_t)g * D_MOD + d0 + c] = s[c];
}

// level 1: superblock sb scans its 32 groups (zero entry). inner[g] = carry entering
// group g within sb; sbsum[sb] = chain value after all 32 groups.
__global__ void k_scan_b1(const float* __restrict__ clast, const float* __restrict__ dl,
                          float* __restrict__ inner, float* __restrict__ sbsum) {
  int d = threadIdx.x;            // 0..767
  int sb = blockIdx.x;            // 0..31
  float dec = fsigmoid(dl[d]);
  float aT = dec;
#pragma unroll
  for (int i = 0; i < 4; i++) aT *= aT;   // decay^16
  const float* cp = clast + (size_t)sb * 32 * D_MOD + d;
  float* ip = inner + (size_t)sb * 32 * D_MOD + d;
  float c = 0.f;
#pragma unroll
  for (int j = 0; j < 32; j++) {          // full unroll: loads batch-issue
    ip[(size_t)j * D_MOD] = c;
    c = fmaf(aT, c, cp[(size_t)j * D_MOD]);
  }
  sbsum[(size_t)sb * D_MOD + d] = c;
}

// level 2: scan the 32 superblock totals. multiplier = decay^(16*32) = decay^512.
__global__ void k_scan_b2(const float* __restrict__ sbsum, const float* __restrict__ dl,
                          float* __restrict__ sbcarry) {
  int d = threadIdx.x;            // 0..767
  float dec = fsigmoid(dl[d]);
  float A = dec;
#pragma unroll
  for (int i = 0; i < 9; i++) A *= A;     // decay^512
  float c = 0.f;
#pragma unroll
  for (int sb = 0; sb < 32; sb++) {
    sbcarry[(size_t)sb * D_MOD + d] = c;
    c = fmaf(A, c, sbsum[(size_t)sb * D_MOD + d]);
  }
}

__global__ void k_scan_c(const bf16* __restrict__ u, const float* __restrict__ dl,
                         const float* __restrict__ inner, const float* __restrict__ sbcarry,
                         bf16* __restrict__ gate_s) {
  int t = threadIdx.x;            // 0..191
  int g = blockIdx.x;
  int d0 = t * 4;
  float dec[4], s[4];
#pragma unroll
  for (int c = 0; c < 4; c++) dec[c] = fsigmoid(dl[d0 + c]);
  // carry entering group g = inner[g] + aTg^(g&31) * sbcarry[g>>5]
  {
    float4 iv = *(const float4*)(inner + (size_t)g * D_MOD + d0);
    float4 sv = *(const float4*)(sbcarry + (size_t)(g >> 5) * D_MOD + d0);
    int e = g & 31;                       // block-uniform
    float pw[4], bs[4];
#pragma unroll
    for (int c = 0; c < 4; c++) {
      float aT = dec[c];
#pragma unroll
      for (int i = 0; i < 4; i++) aT *= aT;   // decay^16
      pw[c] = 1.f; bs[c] = aT;
    }
#pragma unroll
    for (int bit = 0; bit < 5; bit++) {
      if ((e >> bit) & 1) {
#pragma unroll
        for (int c = 0; c < 4; c++) pw[c] *= bs[c];
      }
#pragma unroll
      for (int c = 0; c < 4; c++) bs[c] *= bs[c];
    }
    s[0] = fmaf(pw[0], sv.x, iv.x);
    s[1] = fmaf(pw[1], sv.y, iv.y);
    s[2] = fmaf(pw[2], sv.z, iv.z);
    s[3] = fmaf(pw[3], sv.w, iv.w);
  }
  const ushort4* up = (const ushort4*)(u + (size_t)g * S_T * D_MOD) + t;
  ushort4* gp = (ushort4*)(gate_s + (size_t)g * S_T * D_MOD) + t;
  ushort4 nu = up[0], ng = gp[0];
#pragma unroll 4
  for (int tt = 0; tt < S_T; tt++) {
    ushort4 uv = nu, gv = ng;
    if (tt + 1 < S_T) {
      nu = up[(size_t)(tt + 1) * 192];
      ng = gp[(size_t)(tt + 1) * 192];
    }
    s[0] = fmaf(dec[0], s[0], bf2f(uv.x));
    s[1] = fmaf(dec[1], s[1], bf2f(uv.y));
    s[2] = fmaf(dec[2], s[2], bf2f(uv.z));
    s[3] = fmaf(dec[3], s[3], bf2f(uv.w));
    ushort4 ov;
    ov.x = f2bf(s[0] * bf2f(gv.x));
    ov.y = f2bf(s[1] * bf2f(gv.y));
    ov.z = f2bf(s[2] * bf2f(gv.z));
    ov.w = f2bf(s[3] * bf2f(gv.w));
    gp[(size_t)tt * 192] = ov;
  }
}

// ---------------- final LN: x bf16 + precomputed stats -> f32 out ----------------
__global__ __launch_bounds__(256) void k_ln_final(const u16* __restrict__ x,
    const float* __restrict__ stats, const float* __restrict__ g,
    const float* __restrict__ b, float* __restrict__ outp) {
  int wv = threadIdx.x >> 6, lane = threadIdx.x & 63;
  int row = blockIdx.x * 4 + wv;
  float sv = stats[2 * row], sq = stats[2 * row + 1];
  float mu = sv * (1.0f / (float)D_MOD);
  float var = sq * (1.0f / (float)D_MOD) - mu * mu;
  float rv = 1.0f / sqrtf(var + EPSV);
  const ushort4* xr = (const ushort4*)(x + (size_t)row * D_MOD);
  const float4* g4 = (const float4*)g;
  const float4* b4 = (const float4*)b;
  float4* o4 = (float4*)(outp + (size_t)row * D_MOD);
#pragma unroll
  for (int j = 0; j < 3; j++) {
    int f = j * 64 + lane;
    ushort4 xv = xr[f];
    float4 gg = g4[f], bb = b4[f], ov;
    ov.x = (bf2f(xv.x) - mu) * rv * gg.x + bb.x;
    ov.y = (bf2f(xv.y) - mu) * rv * gg.y + bb.y;
    ov.z = (bf2f(xv.z) - mu) * rv * gg.z + bb.z;
    ov.w = (bf2f(xv.w) - mu) * rv * gg.w + bb.w;
    o4[f] = ov;
  }
}

extern "C" void kernel_launch(void* const* d_in, const int* in_sizes, int n_in,
                              void* d_out, int out_size, void* d_ws, size_t ws_size,
                              hipStream_t stream) {
  const float* nf     = (const float*)d_in[0];
  const float* W_proj = (const float*)d_in[1];
  const float* b_proj = (const float*)d_in[2];
  const float* ln_s_g = (const float*)d_in[3];
  const float* ln_s_b = (const float*)d_in[4];
  const float* W_in   = (const float*)d_in[5];
  const float* b_in   = (const float*)d_in[6];
  const float* W_gate = (const float*)d_in[7];
  const float* b_gate = (const float*)d_in[8];
  const float* W_out  = (const float*)d_in[9];
  const float* b_out  = (const float*)d_in[10];
  const float* dlogit = (const float*)d_in[11];
  const float* ln_f_g = (const float*)d_in[12];
  const float* ln_f_b = (const float*)d_in[13];
  const float* W_ff1  = (const float*)d_in[14];
  const float* b_ff1  = (const float*)d_in[15];
  const float* W_ff2  = (const float*)d_in[16];
  const float* b_ff2  = (const float*)d_in[17];
  const float* ln_o_g = (const float*)d_in[18];
  const float* ln_o_b = (const float*)d_in[19];
  (void)in_sizes; (void)n_in;

  char* ws = (char*)d_ws;
  size_t off = 0;
  auto alloc = [&](size_t bytes) -> char* {
    char* p = ws + off;
    off = (off + bytes + 255) & ~(size_t)255;
    return p;
  };
  const bool big = ws_size >= (160ull << 20);
  const size_t wmul = big ? N_LAYER : 1;

  u16*   x     = (u16*)alloc(2ull * L_TOK * D_MOD);        // residual stream, bf16 (25 MB)
  // shared region (50.3 MB): nfb (pre-loop) | u+gate (recurrence) | tb (FF)
  char*  ug    = alloc(2ull * L_TOK * D_FF);
  u16*   u     = (u16*)ug;
  u16*   gate  = (u16*)(ug + 2ull * L_TOK * D_MOD);
  u16*   tb    = (u16*)ug;
  u16*   nfb   = (u16*)ug;
  bf16*  WprojT= (bf16*)alloc(2ull * D_INP * D_MOD);
  bf16*  WigT  = (bf16*)alloc(2ull * wmul * (2 * D_MOD) * D_MOD);  // [g∘W_in^T ; g∘W_gate^T]
  bf16*  WoT   = (bf16*)alloc(2ull * wmul * D_MOD * D_MOD);
  bf16*  Wff1T = (bf16*)alloc(2ull * wmul * D_MOD * D_FF);
  bf16*  Wff2T = (bf16*)alloc(2ull * wmul * D_FF * D_MOD);
  float* clast = (float*)alloc(sizeof(float) * (size_t)S_G * D_MOD);
  float* carry = (float*)alloc(sizeof(float) * (size_t)S_G * D_MOD);   // inner carries
  float* sbsum = (float*)alloc(sizeof(float) * (size_t)S_SB * D_MOD);
  float* sbcar = (float*)alloc(sizeof(float) * (size_t)S_SB * D_MOD);
  // zeroed region: stats slots [17][16384][2] + fold vectors
  char*  zbase = alloc(0);
  float* stats = (float*)alloc(sizeof(float) * 17ull * L_TOK * 2);     // 2.23 MB
  float* wvig  = (float*)alloc(sizeof(float) * N_LAYER * 2 * D_MOD);   // g_s@[W_in|W_gate]
  float* bvig  = (float*)alloc(sizeof(float) * N_LAYER * 2 * D_MOD);
  float* wvf1  = (float*)alloc(sizeof(float) * N_LAYER * D_FF);        // g_f@W_ff1
  float* bvf1  = (float*)alloc(sizeof(float) * N_LAYER * D_FF);
  size_t zbytes = (size_t)((char*)ws + off - zbase);
  hipMemsetAsync(zbase, 0, zbytes, stream);

  const size_t DD = (size_t)D_MOD * D_MOD, DF = (size_t)D_MOD * D_FF;
  auto statslot = [&](int s) { return stats + (size_t)s * L_TOK * 2; };
  dim3 tb32(32, 8);
  k_f32_to_bf16v<<<(L_TOK * D_INP / 4 + 255) / 256, 256, 0, stream>>>(
      (const float4*)nf, (ushort4*)nfb, L_TOK * D_INP / 4);
  k_transpose_fold<false><<<dim3(D_MOD / 32, D_INP / 32, 1), tb32, 0, stream>>>(
      W_proj, WprojT, D_INP, D_MOD, 0, 0, nullptr, nullptr, nullptr, nullptr, 0);
  if (big) {
    k_transpose_fold<true><<<dim3(D_MOD / 32, D_MOD / 32, N_LAYER), tb32, 0, stream>>>(
        W_in,   WigT,      D_MOD, D_MOD, DD, 2 * DD, ln_s_g, ln_s_b, wvig,       bvig,       2 * D_MOD);
    k_transpose_fold<true><<<dim3(D_MOD / 32, D_MOD / 32, N_LAYER), tb32, 0, stream>>>(
        W_gate, WigT + DD, D_MOD, D_MOD, DD, 2 * DD, ln_s_g, ln_s_b, wvig + D_MOD, bvig + D_MOD, 2 * D_MOD);
    k_transpose_fold<false><<<dim3(D_MOD / 32, D_MOD / 32, N_LAYER), tb32, 0, stream>>>(
        W_out,  WoT,       D_MOD, D_MOD, DD, DD, nullptr, nullptr, nullptr, nullptr, 0);
    k_transpose_fold<true><<<dim3(D_FF / 32,  D_MOD / 32, N_LAYER), tb32, 0, stream>>>(
        W_ff1,  Wff1T,     D_MOD, D_FF,  DF, DF, ln_f_g, ln_f_b, wvf1, bvf1, D_FF);
    k_transpose_fold<false><<<dim3(D_MOD / 32, D_FF / 32,  N_LAYER), tb32, 0, stream>>>(
        W_ff2,  Wff2T,     D_FF,  D_MOD, DF, DF, nullptr, nullptr, nullptr, nullptr, 0);
  }

  // x = nf @ W_proj + b_proj  (bf16 out + stats slot 0)
  k_gemm128<0, false, true><<<128 * 6, 256, 0, stream>>>(
      (const short*)nfb, (const short*)WprojT, b_proj, nullptr, nullptr, nullptr,
      nullptr, statslot(0), nullptr, x, nullptr, D_MOD, D_INP, 6);

  for (int l = 0; l < N_LAYER; l++) {
    const bf16 *wigT, *woT, *wf1T, *wf2T;
    if (big) {
      wigT = WigT  + (size_t)l * 2 * DD;
      woT  = WoT   + (size_t)l * DD;
      wf1T = Wff1T + (size_t)l * DF;
      wf2T = Wff2T + (size_t)l * DF;
    } else {
      k_transpose_fold<true><<<dim3(D_MOD / 32, D_MOD / 32, 1), tb32, 0, stream>>>(
          W_in + (size_t)l * DD, WigT, D_MOD, D_MOD, 0, 0,
          ln_s_g + l * D_MOD, ln_s_b + l * D_MOD, wvig + (size_t)l * 2 * D_MOD, bvig + (size_t)l * 2 * D_MOD, 0);
      k_transpose_fold<true><<<dim3(D_MOD / 32, D_MOD / 32, 1), tb32, 0, stream>>>(
          W_gate + (size_t)l * DD, WigT + DD, D_MOD, D_MOD, 0, 0,
          ln_s_g + l * D_MOD, ln_s_b + l * D_MOD, wvig + (size_t)l * 2 * D_MOD + D_MOD, bvig + (size_t)l * 2 * D_MOD + D_MOD, 0);
      k_transpose_fold<false><<<dim3(D_MOD / 32, D_MOD / 32, 1), tb32, 0, stream>>>(
          W_out + (size_t)l * DD, WoT, D_MOD, D_MOD, 0, 0, nullptr, nullptr, nullptr, nullptr, 0);
      k_transpose_fold<true><<<dim3(D_FF / 32, D_MOD / 32, 1), tb32, 0, stream>>>(
          W_ff1 + (size_t)l * DF, Wff1T, D_MOD, D_FF, 0, 0,
          ln_f_g + l * D_MOD, ln_f_b + l * D_MOD, wvf1 + (size_t)l * D_FF, bvf1 + (size_t)l * D_FF, 0);
      k_transpose_fold<false><<<dim3(D_MOD / 32, D_FF / 32, 1), tb32, 0, stream>>>(
          W_ff2 + (size_t)l * DF, Wff2T, D_FF, D_MOD, 0, 0, nullptr, nullptr, nullptr, nullptr, 0);
      wigT = WigT; woT = WoT; wf1T = Wff1T; wf2T = Wff2T;
    }

    // fused LN_s + (u | gate) GEMM: A = x directly
    k_gemm128<4, true, false><<<128 * 12, 256, 0, stream>>>(
        (const short*)x, (const short*)wigT, b_in + l * D_MOD, b_gate + l * D_MOD,
        wvig + (size_t)l * 2 * D_MOD, bvig + (size_t)l * 2 * D_MOD,
        statslot(2 * l), nullptr, nullptr, u, gate, 2 * D_MOD, D_MOD, 12);
    // chunked scan (hierarchical group-level); s*gate -> gate buffer (bf16)
    k_scan_a<<<S_G, 192, 0, stream>>>((const bf16*)u, dlogit + l * D_MOD, clast);
    k_scan_b1<<<S_G / 32, D_MOD, 0, stream>>>(clast, dlogit + l * D_MOD, carry, sbsum);
    k_scan_b2<<<1, D_MOD, 0, stream>>>(sbsum, dlogit + l * D_MOD, sbcar);
    k_scan_c<<<S_G, 192, 0, stream>>>((const bf16*)u, dlogit + l * D_MOD, carry, sbcar, (bf16*)gate);
    // x = x + sg @ W_out + b_out  (bf16 in-place + stats slot 2l+1)
    k_gemm128<3, false, true><<<128 * 6, 256, 0, stream>>>(
        (const short*)gate, (const short*)woT, b_out + l * D_MOD, nullptr, nullptr, nullptr,
        nullptr, statslot(2 * l + 1), x, x, nullptr, D_MOD, D_MOD, 6);
    // fused LN_f + FF1 (silu): A = x directly
    k_gemm128<2, true, false><<<128 * 12, 256, 0, stream>>>(
        (const short*)x, (const short*)wf1T, b_ff1 + l * D_FF, nullptr,
        wvf1 + (size_t)l * D_FF, bvf1 + (size_t)l * D_FF,
        statslot(2 * l + 1), nullptr, nullptr, tb, nullptr, D_FF, D_MOD, 12);
    // x = x + tb @ W_ff2 + b_ff2  (bf16 in-place + stats slot 2l+2)
    k_gemm128<3, false, true><<<128 * 6, 256, 0, stream>>>(
        (const short*)tb, (const short*)wf2T, b_ff2 + l * D_MOD, nullptr, nullptr, nullptr,
        nullptr, statslot(2 * l + 2), x, x, nullptr, D_MOD, D_FF, 6);
  }

  // out = LN_o(x) (f32) using stats slot 16
  k_ln_final<<<L_TOK / 4, 256, 0, stream>>>(x, statslot(2 * N_LAYER), ln_o_g, ln_o_b, (float*)d_out);
}

// Round 11
// 2141.762 us; speedup vs baseline: 1.2711x; 1.0168x over previous
//
#include <hip/hip_runtime.h>
#include <hip/hip_bf16.h>
#include <math.h>
#include <string.h>

#define L_TOK 16384
#define D_INP 256
#define D_MOD 768
#define D_FF  1536
#define N_LAYER 8
#define S_T 16
#define S_G 1024
#define S_SB 32
#define EPSV 1e-5f

typedef short bf16x8 __attribute__((ext_vector_type(8)));
typedef float f32x4 __attribute__((ext_vector_type(4)));
typedef __hip_bfloat16 bf16;
typedef unsigned int u32;
typedef unsigned short u16;

__device__ __forceinline__ float fsigmoid(float z) { return 1.0f / (1.0f + __expf(-z)); }

__device__ __forceinline__ u16 f2bf(float f) {
  __hip_bfloat16 h = __float2bfloat16(f);
  u16 r; memcpy(&r, &h, 2); return r;
}
__device__ __forceinline__ float bf2f(u16 v) {
  u32 x = ((u32)v) << 16; float f; memcpy(&f, &x, 4); return f;
}

// async global->LDS, 16B per lane. LDS dest = (wave-uniform base) + lane*16.
__device__ __forceinline__ void glds16(const short* g, short* l) {
  __builtin_amdgcn_global_load_lds(
      (const __attribute__((address_space(1))) unsigned int*)(g),
      (__attribute__((address_space(3))) unsigned int*)(l), 16, 0, 0);
}

// inline-asm ds_read_b128, opaque to the compiler's waitcnt pass (round-3 lesson:
// compiler-visible LDS reads force a conservative vmcnt(0) drain against outstanding
// global_load_lds). Completion enforced manually: s_waitcnt lgkmcnt(0) +
// sched_barrier(0) (rule 18) before the MFMA cluster.
__device__ __forceinline__ bf16x8 dsr128(const char* base, int imm) {
  bf16x8 r;
  const __attribute__((address_space(3))) char* p =
      (const __attribute__((address_space(3))) char*)base;
  asm volatile("ds_read_b128 %0, %1 offset:%c2" : "=v"(r) : "v"(p), "i"(imm));
  return r;
}

// ---------------- f32 -> bf16, vectorized ----------------
__global__ void k_f32_to_bf16v(const float4* __restrict__ src, ushort4* __restrict__ dst, int n4) {
  int i = blockIdx.x * blockDim.x + threadIdx.x;
  if (i < n4) {
    float4 v = src[i];
    ushort4 o; o.x = f2bf(v.x); o.y = f2bf(v.y); o.z = f2bf(v.z); o.w = f2bf(v.w);
    dst[i] = o;
  }
}

// ------- transpose+convert (+optional LN-fold): src [z][R,C] f32 -> dst [z][C,R] bf16
template<bool FOLD>
__global__ void k_transpose_fold(const float* __restrict__ src, bf16* __restrict__ dst,
                                 int R, int C, size_t sstride, size_t dstride,
                                 const float* __restrict__ gv, const float* __restrict__ bv,
                                 float* __restrict__ wacc, float* __restrict__ bacc,
                                 int vstride) {
  __shared__ float tile[32][33];
  int z = blockIdx.z;
  const float* s = src + (size_t)z * sstride;
  bf16* d = dst + (size_t)z * dstride;
  int r0 = blockIdx.y * 32, c0 = blockIdx.x * 32;
  int tx = threadIdx.x, ty = threadIdx.y;
#pragma unroll
  for (int i = ty; i < 32; i += 8)
    tile[i][tx] = s[(size_t)(r0 + i) * C + (c0 + tx)];
  __syncthreads();
  float gk = 1.0f;
  if (FOLD) gk = gv[(size_t)z * R + r0 + tx];
#pragma unroll
  for (int i = ty; i < 32; i += 8) {
    float val = tile[tx][i];
    if (FOLD) val *= gk;
    d[(size_t)(c0 + i) * R + (r0 + tx)] = __float2bfloat16(val);
  }
  if (FOLD && ty == 0) {
    const float* gz = gv + (size_t)z * R + r0;
    const float* bz = bv + (size_t)z * R + r0;
    float s1 = 0.f, s2 = 0.f;
#pragma unroll 8
    for (int j = 0; j < 32; j++) {
      float wv = tile[j][tx];
      s1 += gz[j] * wv;
      s2 += bz[j] * wv;
    }
    atomicAdd(&wacc[(size_t)z * vstride + c0 + tx], s1);
    atomicAdd(&bacc[(size_t)z * vstride + c0 + tx], s2);
  }
}

// ---------------- bf16 MFMA GEMM: 128x128 tile, BK=32, 4 blocks/CU ----
// m97-faithful occupancy: 2 LDS buffers (33KB -> 4 blocks/CU, 16 waves/CU) with
// depth-1 staging, + round-5 asm ds_reads and explicit counted waits. The round-5
// 3-buffer depth-2 variant (49KB -> 3 blocks/CU) traded the 4th resident block for
// prefetch depth and gained only +2.4%; m114 says wave-level TLP already provides
// the overlap, and m97's 23 B/cy/CU staging rate came from 4 blocks/CU.
// Per iter: {stg(t+1) -> asm reads buf[t&1] -> lgkmcnt(0)+sched_barrier ->
//            16 MFMA -> vmcnt(0) -> barrier}.
// MODE: 0 bias; 2 silu; 3 bias+residual(bf16,in-place); 4 split u|gate.
// LNFOLD: A is raw residual x; val = rv*acc - rv*mu*wvec[gn] + bvec[gn] + bias.
// STATS: per-row sum/sumsq of written bf16 into stats_out (pre-zeroed).
template<int MODE, bool LNFOLD, bool STATS>
__global__ __launch_bounds__(256, 4) void k_gemm128(
    const short* __restrict__ A, const short* __restrict__ Bt,
    const float* __restrict__ bias, const float* __restrict__ bias2,
    const float* __restrict__ wvec, const float* __restrict__ bvec,
    const float* __restrict__ stats_in, float* __restrict__ stats_out,
    u16* __restrict__ res, u16* __restrict__ outp, u16* __restrict__ outp2,
    int N, int K, int ncol)
{
  __shared__ short As[2][128 * 32];
  __shared__ short Bs[2][128 * 32];
  __shared__ float s_mu[128], s_rv[128];
  const int tid = threadIdx.x;
  const int lane = tid & 63, w = tid >> 6;
  const int wr = w >> 1, wc = w & 1;
  const int l16 = lane & 15, qd = lane >> 4;

  const int b = blockIdx.x;
  const int xcd = b & 7, t = b >> 3;
  const int m0 = (xcd * 16 + t / ncol) * 128;
  const int n0 = (t % ncol) * 128;

  const int sr = lane >> 2, sc = lane & 3;
  const int ar = w * 32 + sr;
  const int acx = sc ^ ((ar >> 1) & 3);
  const short* ag0 = A  + (size_t)(m0 + ar) * K + acx * 8;
  const short* ag1 = ag0 + (size_t)16 * K;
  const short* bg0 = Bt + (size_t)(n0 + ar) * K + acx * 8;
  const short* bg1 = bg0 + (size_t)16 * K;

  auto stg = [&](int bi, int k0) {
    short* a0 = &As[bi][w * 1024];
    glds16(ag0 + k0, a0); glds16(ag1 + k0, a0 + 512);
    short* b0 = &Bs[bi][w * 1024];
    glds16(bg0 + k0, b0); glds16(bg1 + k0, b0 + 512);
  };

  const int fo = (qd ^ ((l16 >> 1) & 3)) * 8 + l16 * 32;

  // LN stats load issued first (oldest VMEM; waits stay counted, no queue drain)
  float sv = 0.f, sq = 0.f;
  if (LNFOLD && tid < 128) {
    sv = stats_in[2 * (m0 + tid)];
    sq = stats_in[2 * (m0 + tid) + 1];
  }

  const int NT = K >> 5;   // K is 256, 768 or 1536 -> NT >= 8
  // prologue: tile 0 only (depth-1)
  stg(0, 0);

  if (LNFOLD && tid < 128) {
    float mu  = sv * (1.0f / (float)D_MOD);
    float var = sq * (1.0f / (float)D_MOD) - mu * mu;
    s_mu[tid] = mu;
    s_rv[tid] = 1.0f / sqrtf(var + EPSV);
  }

  f32x4 acc[4][4];
#pragma unroll
  for (int i = 0; i < 4; i++)
#pragma unroll
    for (int j = 0; j < 4; j++) acc[i][j] = (f32x4){0.f, 0.f, 0.f, 0.f};

  // tile 0 landed, publish to all waves
  asm volatile("s_waitcnt vmcnt(0)" ::: "memory");
  __builtin_amdgcn_s_barrier();

  for (int t2 = 0; t2 < NT; ++t2) {
    const int rd = t2 & 1;
    // stage tile t+1 into the buffer tile t-1 vacated (reads of t-1 completed
    // before the barrier ending iter t-1, which precedes this issue)
    if (t2 + 1 < NT) stg(rd ^ 1, (t2 + 1) * 32);
    const char* ab = (const char*)&As[rd][wr * 2048 + fo];
    const char* bb2 = (const char*)&Bs[rd][wc * 2048 + fo];
    bf16x8 af0 = dsr128(ab, 0),    af1 = dsr128(ab, 1024);
    bf16x8 af2 = dsr128(ab, 2048), af3 = dsr128(ab, 3072);
    bf16x8 bf0 = dsr128(bb2, 0),    bf1 = dsr128(bb2, 1024);
    bf16x8 bf2 = dsr128(bb2, 2048), bf3 = dsr128(bb2, 3072);
    asm volatile("s_waitcnt lgkmcnt(0)" ::: "memory");
    __builtin_amdgcn_sched_barrier(0);
    bf16x8 af[4] = {af0, af1, af2, af3};
    bf16x8 bfr[4] = {bf0, bf1, bf2, bf3};
#pragma unroll
    for (int rt = 0; rt < 4; rt++)
#pragma unroll
      for (int ct = 0; ct < 4; ct++)
        acc[rt][ct] = __builtin_amdgcn_mfma_f32_16x16x32_bf16(af[rt], bfr[ct], acc[rt][ct], 0, 0, 0);
    // tile t+1 must be fully landed before any wave reads it next iter
    asm volatile("s_waitcnt vmcnt(0)" ::: "memory");
    __builtin_amdgcn_s_barrier();
  }

  // ---- epilogue. C/D map col=lane&15, row=(lane>>4)*4+reg ----
  const float* bb = bias;
  u16* op = outp;
  int nofs = 0, Nout = N;
  bool sig = false;
  if (MODE == 4) {
    Nout = N >> 1;
    if (n0 >= Nout) { bb = bias2; op = outp2; nofs = Nout; sig = true; }
  }
  const int gmb = m0 + wr * 64 + qd * 4;
  const int gnb = n0 + wc * 64 + l16;
  float bc[4], wv4[4], bv4[4];
#pragma unroll
  for (int ct = 0; ct < 4; ct++) {
    int gn = gnb + ct * 16;
    bc[ct] = bb[gn - nofs];
    if (LNFOLD) { wv4[ct] = wvec[gn]; bv4[ct] = bvec[gn]; }
  }
#pragma unroll
  for (int rt = 0; rt < 4; rt++) {
#pragma unroll
    for (int r = 0; r < 4; r++) {
      const int gm = gmb + rt * 16 + r;
      float mu = 0.f, rv = 0.f;
      if (LNFOLD) { mu = s_mu[gm - m0]; rv = s_rv[gm - m0]; }
      float ps = 0.f, ps2 = 0.f;
#pragma unroll
      for (int ct = 0; ct < 4; ct++) {
        int gn = gnb + ct * 16;
        float vv = acc[rt][ct][r];
        if (LNFOLD) vv = rv * vv - rv * mu * wv4[ct] + bv4[ct] + bc[ct];
        else        vv += bc[ct];
        if (MODE == 2) vv = vv * fsigmoid(vv);
        if (MODE == 4 && sig) vv = fsigmoid(vv);
        size_t oidx = (size_t)gm * Nout + (gn - nofs);
        if (MODE == 3) vv += bf2f(res[oidx]);
        u16 rb = f2bf(vv);
        op[oidx] = rb;
        if (STATS) { float fv = bf2f(rb); ps += fv; ps2 += fv * fv; }
      }
      if (STATS) {
#pragma unroll
        for (int o = 1; o < 16; o <<= 1) {
          ps  += __shfl_xor(ps, o, 64);
          ps2 += __shfl_xor(ps2, o, 64);
        }
        if (l16 == 0) {
          atomicAdd(&stats_out[2 * gm], ps);
          atomicAdd(&stats_out[2 * gm + 1], ps2);
        }
      }
    }
  }
}

// ---------------- chunked linear-recurrence scan (u bf16, 4 ch/thread) ----------------
// S_T=16, S_G=1024 (4 blocks/CU TLP for a/c); hierarchical group-level scan
// (b1: 32 superblocks x 32 groups, b2: 32 superblock totals) -- round-10 verified.
__global__ void k_scan_a(const bf16* __restrict__ u, const float* __restrict__ dl,
                         float* __restrict__ clast) {
  int t = threadIdx.x;            // 0..191
  int g = blockIdx.x;
  int d0 = t * 4;
  float dec[4], s[4] = {0.f, 0.f, 0.f, 0.f};
#pragma unroll
  for (int c = 0; c < 4; c++) dec[c] = fsigmoid(dl[d0 + c]);
  const ushort4* up = (const ushort4*)(u + (size_t)g * S_T * D_MOD) + t;
  ushort4 nxt = up[0];
#pragma unroll 4
  for (int tt = 0; tt < S_T; tt++) {
    ushort4 uv = nxt;
    if (tt + 1 < S_T) nxt = up[(size_t)(tt + 1) * 192];
    s[0] = fmaf(dec[0], s[0], bf2f(uv.x));
    s[1] = fmaf(dec[1], s[1], bf2f(uv.y));
    s[2] = fmaf(dec[2], s[2], bf2f(uv.z));
    s[3] = fmaf(dec[3], s[3], bf2f(uv.w));
  }
#pragma unroll
  for (int c = 0; c < 4; c++) clast[(size_t)g * D_MOD + d0 + c] = s[c];
}

// level 1: superblock sb scans its 32 groups (zero entry). inner[g] = carry entering
// group g within sb; sbsum[sb] = chain value after all 32 groups.
__global__ void k_scan_b1(const float* __restrict__ clast, const float* __restrict__ dl,
                          float* __restrict__ inner, float* __restrict__ sbsum) {
  int d = threadIdx.x;            // 0..767
  int sb = blockIdx.x;            // 0..31
  float dec = fsigmoid(dl[d]);
  float aT = dec;
#pragma unroll
  for (int i = 0; i < 4; i++) aT *= aT;   // decay^16
  const float* cp = clast + (size_t)sb * 32 * D_MOD + d;
  float* ip = inner + (size_t)sb * 32 * D_MOD + d;
  float c = 0.f;
#pragma unroll
  for (int j = 0; j < 32; j++) {          // full unroll: loads batch-issue
    ip[(size_t)j * D_MOD] = c;
    c = fmaf(aT, c, cp[(size_t)j * D_MOD]);
  }
  sbsum[(size_t)sb * D_MOD + d] = c;
}

// level 2: scan the 32 superblock totals. multiplier = decay^(16*32) = decay^512.
__global__ void k_scan_b2(const float* __restrict__ sbsum, const float* __restrict__ dl,
                          float* __restrict__ sbcarry) {
  int d = threadIdx.x;            // 0..767
  float dec = fsigmoid(dl[d]);
  float A = dec;
#pragma unroll
  for (int i = 0; i < 9; i++) A *= A;     // decay^512
  float c = 0.f;
#pragma unroll
  for (int sb = 0; sb < 32; sb++) {
    sbcarry[(size_t)sb * D_MOD + d] = c;
    c = fmaf(A, c, sbsum[(size_t)sb * D_MOD + d]);
  }
}

__global__ void k_scan_c(const bf16* __restrict__ u, const float* __restrict__ dl,
                         const float* __restrict__ inner, const float* __restrict__ sbcarry,
                         bf16* __restrict__ gate_s) {
  int t = threadIdx.x;            // 0..191
  int g = blockIdx.x;
  int d0 = t * 4;
  float dec[4], s[4];
#pragma unroll
  for (int c = 0; c < 4; c++) dec[c] = fsigmoid(dl[d0 + c]);
  // carry entering group g = inner[g] + aTg^(g&31) * sbcarry[g>>5]
  {
    float4 iv = *(const float4*)(inner + (size_t)g * D_MOD + d0);
    float4 sv = *(const float4*)(sbcarry + (size_t)(g >> 5) * D_MOD + d0);
    int e = g & 31;                       // block-uniform
    float pw[4], bs[4];
#pragma unroll
    for (int c = 0; c < 4; c++) {
      float aT = dec[c];
#pragma unroll
      for (int i = 0; i < 4; i++) aT *= aT;   // decay^16
      pw[c] = 1.f; bs[c] = aT;
    }
#pragma unroll
    for (int bit = 0; bit < 5; bit++) {
      if ((e >> bit) & 1) {
#pragma unroll
        for (int c = 0; c < 4; c++) pw[c] *= bs[c];
      }
#pragma unroll
      for (int c = 0; c < 4; c++) bs[c] *= bs[c];
    }
    s[0] = fmaf(pw[0], sv.x, iv.x);
    s[1] = fmaf(pw[1], sv.y, iv.y);
    s[2] = fmaf(pw[2], sv.z, iv.z);
    s[3] = fmaf(pw[3], sv.w, iv.w);
  }
  const ushort4* up = (const ushort4*)(u + (size_t)g * S_T * D_MOD) + t;
  ushort4* gp = (ushort4*)(gate_s + (size_t)g * S_T * D_MOD) + t;
  ushort4 nu = up[0], ng = gp[0];
#pragma unroll 4
  for (int tt = 0; tt < S_T; tt++) {
    ushort4 uv = nu, gv = ng;
    if (tt + 1 < S_T) {
      nu = up[(size_t)(tt + 1) * 192];
      ng = gp[(size_t)(tt + 1) * 192];
    }
    s[0] = fmaf(dec[0], s[0], bf2f(uv.x));
    s[1] = fmaf(dec[1], s[1], bf2f(uv.y));
    s[2] = fmaf(dec[2], s[2], bf2f(uv.z));
    s[3] = fmaf(dec[3], s[3], bf2f(uv.w));
    ushort4 ov;
    ov.x = f2bf(s[0] * bf2f(gv.x));
    ov.y = f2bf(s[1] * bf2f(gv.y));
    ov.z = f2bf(s[2] * bf2f(gv.z));
    ov.w = f2bf(s[3] * bf2f(gv.w));
    gp[(size_t)tt * 192] = ov;
  }
}

// ---------------- final LN: x bf16 + precomputed stats -> f32 out ----------------
__global__ __launch_bounds__(256) void k_ln_final(const u16* __restrict__ x,
    const float* __restrict__ stats, const float* __restrict__ g,
    const float* __restrict__ b, float* __restrict__ outp) {
  int wv = threadIdx.x >> 6, lane = threadIdx.x & 63;
  int row = blockIdx.x * 4 + wv;
  float sv = stats[2 * row], sq = stats[2 * row + 1];
  float mu = sv * (1.0f / (float)D_MOD);
  float var = sq * (1.0f / (float)D_MOD) - mu * mu;
  float rv = 1.0f / sqrtf(var + EPSV);
  const ushort4* xr = (const ushort4*)(x + (size_t)row * D_MOD);
  const float4* g4 = (const float4*)g;
  const float4* b4 = (const float4*)b;
  float4* o4 = (float4*)(outp + (size_t)row * D_MOD);
#pragma unroll
  for (int j = 0; j < 3; j++) {
    int f = j * 64 + lane;
    ushort4 xv = xr[f];
    float4 gg = g4[f], bb = b4[f], ov;
    ov.x = (bf2f(xv.x) - mu) * rv * gg.x + bb.x;
    ov.y = (bf2f(xv.y) - mu) * rv * gg.y + bb.y;
    ov.z = (bf2f(xv.z) - mu) * rv * gg.z + bb.z;
    ov.w = (bf2f(xv.w) - mu) * rv * gg.w + bb.w;
    o4[f] = ov;
  }
}

extern "C" void kernel_launch(void* const* d_in, const int* in_sizes, int n_in,
                              void* d_out, int out_size, void* d_ws, size_t ws_size,
                              hipStream_t stream) {
  const float* nf     = (const float*)d_in[0];
  const float* W_proj = (const float*)d_in[1];
  const float* b_proj = (const float*)d_in[2];
  const float* ln_s_g = (const float*)d_in[3];
  const float* ln_s_b = (const float*)d_in[4];
  const float* W_in   = (const float*)d_in[5];
  const float* b_in   = (const float*)d_in[6];
  const float* W_gate = (const float*)d_in[7];
  const float* b_gate = (const float*)d_in[8];
  const float* W_out  = (const float*)d_in[9];
  const float* b_out  = (const float*)d_in[10];
  const float* dlogit = (const float*)d_in[11];
  const float* ln_f_g = (const float*)d_in[12];
  const float* ln_f_b = (const float*)d_in[13];
  const float* W_ff1  = (const float*)d_in[14];
  const float* b_ff1  = (const float*)d_in[15];
  const float* W_ff2  = (const float*)d_in[16];
  const float* b_ff2  = (const float*)d_in[17];
  const float* ln_o_g = (const float*)d_in[18];
  const float* ln_o_b = (const float*)d_in[19];
  (void)in_sizes; (void)n_in;

  char* ws = (char*)d_ws;
  size_t off = 0;
  auto alloc = [&](size_t bytes) -> char* {
    char* p = ws + off;
    off = (off + bytes + 255) & ~(size_t)255;
    return p;
  };
  const bool big = ws_size >= (160ull << 20);
  const size_t wmul = big ? N_LAYER : 1;

  u16*   x     = (u16*)alloc(2ull * L_TOK * D_MOD);        // residual stream, bf16 (25 MB)
  // shared region (50.3 MB): nfb (pre-loop) | u+gate (recurrence) | tb (FF)
  char*  ug    = alloc(2ull * L_TOK * D_FF);
  u16*   u     = (u16*)ug;
  u16*   gate  = (u16*)(ug + 2ull * L_TOK * D_MOD);
  u16*   tb    = (u16*)ug;
  u16*   nfb   = (u16*)ug;
  bf16*  WprojT= (bf16*)alloc(2ull * D_INP * D_MOD);
  bf16*  WigT  = (bf16*)alloc(2ull * wmul * (2 * D_MOD) * D_MOD);  // [g∘W_in^T ; g∘W_gate^T]
  bf16*  WoT   = (bf16*)alloc(2ull * wmul * D_MOD * D_MOD);
  bf16*  Wff1T = (bf16*)alloc(2ull * wmul * D_MOD * D_FF);
  bf16*  Wff2T = (bf16*)alloc(2ull * wmul * D_FF * D_MOD);
  float* clast = (float*)alloc(sizeof(float) * (size_t)S_G * D_MOD);
  float* carry = (float*)alloc(sizeof(float) * (size_t)S_G * D_MOD);   // inner carries
  float* sbsum = (float*)alloc(sizeof(float) * (size_t)S_SB * D_MOD);
  float* sbcar = (float*)alloc(sizeof(float) * (size_t)S_SB * D_MOD);
  // zeroed region: stats slots [17][16384][2] + fold vectors
  char*  zbase = alloc(0);
  float* stats = (float*)alloc(sizeof(float) * 17ull * L_TOK * 2);     // 2.23 MB
  float* wvig  = (float*)alloc(sizeof(float) * N_LAYER * 2 * D_MOD);   // g_s@[W_in|W_gate]
  float* bvig  = (float*)alloc(sizeof(float) * N_LAYER * 2 * D_MOD);
  float* wvf1  = (float*)alloc(sizeof(float) * N_LAYER * D_FF);        // g_f@W_ff1
  float* bvf1  = (float*)alloc(sizeof(float) * N_LAYER * D_FF);
  size_t zbytes = (size_t)((char*)ws + off - zbase);
  hipMemsetAsync(zbase, 0, zbytes, stream);

  const size_t DD = (size_t)D_MOD * D_MOD, DF = (size_t)D_MOD * D_FF;
  auto statslot = [&](int s) { return stats + (size_t)s * L_TOK * 2; };
  dim3 tb32(32, 8);
  k_f32_to_bf16v<<<(L_TOK * D_INP / 4 + 255) / 256, 256, 0, stream>>>(
      (const float4*)nf, (ushort4*)nfb, L_TOK * D_INP / 4);
  k_transpose_fold<false><<<dim3(D_MOD / 32, D_INP / 32, 1), tb32, 0, stream>>>(
      W_proj, WprojT, D_INP, D_MOD, 0, 0, nullptr, nullptr, nullptr, nullptr, 0);
  if (big) {
    k_transpose_fold<true><<<dim3(D_MOD / 32, D_MOD / 32, N_LAYER), tb32, 0, stream>>>(
        W_in,   WigT,      D_MOD, D_MOD, DD, 2 * DD, ln_s_g, ln_s_b, wvig,       bvig,       2 * D_MOD);
    k_transpose_fold<true><<<dim3(D_MOD / 32, D_MOD / 32, N_LAYER), tb32, 0, stream>>>(
        W_gate, WigT + DD, D_MOD, D_MOD, DD, 2 * DD, ln_s_g, ln_s_b, wvig + D_MOD, bvig + D_MOD, 2 * D_MOD);
    k_transpose_fold<false><<<dim3(D_MOD / 32, D_MOD / 32, N_LAYER), tb32, 0, stream>>>(
        W_out,  WoT,       D_MOD, D_MOD, DD, DD, nullptr, nullptr, nullptr, nullptr, 0);
    k_transpose_fold<true><<<dim3(D_FF / 32,  D_MOD / 32, N_LAYER), tb32, 0, stream>>>(
        W_ff1,  Wff1T,     D_MOD, D_FF,  DF, DF, ln_f_g, ln_f_b, wvf1, bvf1, D_FF);
    k_transpose_fold<false><<<dim3(D_MOD / 32, D_FF / 32,  N_LAYER), tb32, 0, stream>>>(
        W_ff2,  Wff2T,     D_FF,  D_MOD, DF, DF, nullptr, nullptr, nullptr, nullptr, 0);
  }

  // x = nf @ W_proj + b_proj  (bf16 out + stats slot 0)
  k_gemm128<0, false, true><<<128 * 6, 256, 0, stream>>>(
      (const short*)nfb, (const short*)WprojT, b_proj, nullptr, nullptr, nullptr,
      nullptr, statslot(0), nullptr, x, nullptr, D_MOD, D_INP, 6);

  for (int l = 0; l < N_LAYER; l++) {
    const bf16 *wigT, *woT, *wf1T, *wf2T;
    if (big) {
      wigT = WigT  + (size_t)l * 2 * DD;
      woT  = WoT   + (size_t)l * DD;
      wf1T = Wff1T + (size_t)l * DF;
      wf2T = Wff2T + (size_t)l * DF;
    } else {
      k_transpose_fold<true><<<dim3(D_MOD / 32, D_MOD / 32, 1), tb32, 0, stream>>>(
          W_in + (size_t)l * DD, WigT, D_MOD, D_MOD, 0, 0,
          ln_s_g + l * D_MOD, ln_s_b + l * D_MOD, wvig + (size_t)l * 2 * D_MOD, bvig + (size_t)l * 2 * D_MOD, 0);
      k_transpose_fold<true><<<dim3(D_MOD / 32, D_MOD / 32, 1), tb32, 0, stream>>>(
          W_gate + (size_t)l * DD, WigT + DD, D_MOD, D_MOD, 0, 0,
          ln_s_g + l * D_MOD, ln_s_b + l * D_MOD, wvig + (size_t)l * 2 * D_MOD + D_MOD, bvig + (size_t)l * 2 * D_MOD + D_MOD, 0);
      k_transpose_fold<false><<<dim3(D_MOD / 32, D_MOD / 32, 1), tb32, 0, stream>>>(
          W_out + (size_t)l * DD, WoT, D_MOD, D_MOD, 0, 0, nullptr, nullptr, nullptr, nullptr, 0);
      k_transpose_fold<true><<<dim3(D_FF / 32, D_MOD / 32, 1), tb32, 0, stream>>>(
          W_ff1 + (size_t)l * DF, Wff1T, D_MOD, D_FF, 0, 0,
          ln_f_g + l * D_MOD, ln_f_b + l * D_MOD, wvf1 + (size_t)l * D_FF, bvf1 + (size_t)l * D_FF, 0);
      k_transpose_fold<false><<<dim3(D_MOD / 32, D_FF / 32, 1), tb32, 0, stream>>>(
          W_ff2 + (size_t)l * DF, Wff2T, D_FF, D_MOD, 0, 0, nullptr, nullptr, nullptr, nullptr, 0);
      wigT = WigT; woT = WoT; wf1T = Wff1T; wf2T = Wff2T;
    }

    // fused LN_s + (u | gate) GEMM: A = x directly
    k_gemm128<4, true, false><<<128 * 12, 256, 0, stream>>>(
        (const short*)x, (const short*)wigT, b_in + l * D_MOD, b_gate + l * D_MOD,
        wvig + (size_t)l * 2 * D_MOD, bvig + (size_t)l * 2 * D_MOD,
        statslot(2 * l), nullptr, nullptr, u, gate, 2 * D_MOD, D_MOD, 12);
    // chunked scan (hierarchical group-level); s*gate -> gate buffer (bf16)
    k_scan_a<<<S_G, 192, 0, stream>>>((const bf16*)u, dlogit + l * D_MOD, clast);
    k_scan_b1<<<S_G / 32, D_MOD, 0, stream>>>(clast, dlogit + l * D_MOD, carry, sbsum);
    k_scan_b2<<<1, D_MOD, 0, stream>>>(sbsum, dlogit + l * D_MOD, sbcar);
    k_scan_c<<<S_G, 192, 0, stream>>>((const bf16*)u, dlogit + l * D_MOD, carry, sbcar, (bf16*)gate);
    // x = x + sg @ W_out + b_out  (bf16 in-place + stats slot 2l+1)
    k_gemm128<3, false, true><<<128 * 6, 256, 0, stream>>>(
        (const short*)gate, (const short*)woT, b_out + l * D_MOD, nullptr, nullptr, nullptr,
        nullptr, statslot(2 * l + 1), x, x, nullptr, D_MOD, D_MOD, 6);
    // fused LN_f + FF1 (silu): A = x directly
    k_gemm128<2, true, false><<<128 * 12, 256, 0, stream>>>(
        (const short*)x, (const short*)wf1T, b_ff1 + l * D_FF, nullptr,
        wvf1 + (size_t)l * D_FF, bvf1 + (size_t)l * D_FF,
        statslot(2 * l + 1), nullptr, nullptr, tb, nullptr, D_FF, D_MOD, 12);
    // x = x + tb @ W_ff2 + b_ff2  (bf16 in-place + stats slot 2l+2)
    k_gemm128<3, false, true><<<128 * 6, 256, 0, stream>>>(
        (const short*)tb, (const short*)wf2T, b_ff2 + l * D_MOD, nullptr, nullptr, nullptr,
        nullptr, statslot(2 * l + 2), x, x, nullptr, D_MOD, D_FF, 6);
  }

  // out = LN_o(x) (f32) using stats slot 16
  k_ln_final<<<L_TOK / 4, 256, 0, stream>>>(x, statslot(2 * N_LAYER), ln_o_g, ln_o_b, (float*)d_out);
}

// Round 13
// 2101.304 us; speedup vs baseline: 1.2956x; 1.0193x over previous
//
#include <hip/hip_runtime.h>
#include <hip/hip_bf16.h>
#include <math.h>
#include <string.h>

#define L_TOK 16384
#define D_INP 256
#define D_MOD 768
#define D_FF  1536
#define N_LAYER 8
#define S_T 16
#define S_G 1024
#define S_SB 32
#define EPSV 1e-5f

typedef short bf16x8 __attribute__((ext_vector_type(8)));
typedef float f32x4 __attribute__((ext_vector_type(4)));
typedef __hip_bfloat16 bf16;
typedef unsigned int u32;
typedef unsigned short u16;

__device__ __forceinline__ float fsigmoid(float z) { return 1.0f / (1.0f + __expf(-z)); }

__device__ __forceinline__ u16 f2bf(float f) {
  __hip_bfloat16 h = __float2bfloat16(f);
  u16 r; memcpy(&r, &h, 2); return r;
}
__device__ __forceinline__ float bf2f(u16 v) {
  u32 x = ((u32)v) << 16; float f; memcpy(&f, &x, 4); return f;
}

// async global->LDS, 16B per lane. LDS dest = (wave-uniform base) + lane*16.
__device__ __forceinline__ void glds16(const short* g, short* l) {
  __builtin_amdgcn_global_load_lds(
      (const __attribute__((address_space(1))) unsigned int*)(g),
      (__attribute__((address_space(3))) unsigned int*)(l), 16, 0, 0);
}

// inline-asm ds_read_b128, opaque to the compiler's waitcnt pass (round-3 lesson:
// compiler-visible LDS reads force a conservative vmcnt(0) drain against outstanding
// global_load_lds). Completion enforced manually: s_waitcnt lgkmcnt(0) +
// sched_barrier(0) (rule 18) before the MFMA cluster.
__device__ __forceinline__ bf16x8 dsr128(const char* base, int imm) {
  bf16x8 r;
  const __attribute__((address_space(3))) char* p =
      (const __attribute__((address_space(3))) char*)base;
  asm volatile("ds_read_b128 %0, %1 offset:%c2" : "=v"(r) : "v"(p), "i"(imm));
  return r;
}

// ---------------- f32 -> bf16, vectorized ----------------
__global__ void k_f32_to_bf16v(const float4* __restrict__ src, ushort4* __restrict__ dst, int n4) {
  int i = blockIdx.x * blockDim.x + threadIdx.x;
  if (i < n4) {
    float4 v = src[i];
    ushort4 o; o.x = f2bf(v.x); o.y = f2bf(v.y); o.z = f2bf(v.z); o.w = f2bf(v.w);
    dst[i] = o;
  }
}

// ------- transpose+convert (+optional LN-fold): src [z][R,C] f32 -> dst [z][C,R] bf16
template<bool FOLD>
__global__ void k_transpose_fold(const float* __restrict__ src, bf16* __restrict__ dst,
                                 int R, int C, size_t sstride, size_t dstride,
                                 const float* __restrict__ gv, const float* __restrict__ bv,
                                 float* __restrict__ wacc, float* __restrict__ bacc,
                                 int vstride) {
  __shared__ float tile[32][33];
  int z = blockIdx.z;
  const float* s = src + (size_t)z * sstride;
  bf16* d = dst + (size_t)z * dstride;
  int r0 = blockIdx.y * 32, c0 = blockIdx.x * 32;
  int tx = threadIdx.x, ty = threadIdx.y;
#pragma unroll
  for (int i = ty; i < 32; i += 8)
    tile[i][tx] = s[(size_t)(r0 + i) * C + (c0 + tx)];
  __syncthreads();
  float gk = 1.0f;
  if (FOLD) gk = gv[(size_t)z * R + r0 + tx];
#pragma unroll
  for (int i = ty; i < 32; i += 8) {
    float val = tile[tx][i];
    if (FOLD) val *= gk;
    d[(size_t)(c0 + i) * R + (r0 + tx)] = __float2bfloat16(val);
  }
  if (FOLD && ty == 0) {
    const float* gz = gv + (size_t)z * R + r0;
    const float* bz = bv + (size_t)z * R + r0;
    float s1 = 0.f, s2 = 0.f;
#pragma unroll 8
    for (int j = 0; j < 32; j++) {
      float wv = tile[j][tx];
      s1 += gz[j] * wv;
      s2 += bz[j] * wv;
    }
    atomicAdd(&wacc[(size_t)z * vstride + c0 + tx], s1);
    atomicAdd(&bacc[(size_t)z * vstride + c0 + tx], s2);
  }
}

// ---------------- bf16 MFMA GEMM: 128x128 tile, BK=32, 4 blocks/CU ----
// Round-11 proven form (67.7us @ N=1536, best of 6 schedule variants): 2 LDS
// buffers (33KB -> 4 blocks/CU), depth-1 staging, asm ds_reads + explicit
// lgkmcnt(0)+sched_barrier, one vmcnt(0)+barrier per iter.
// MODE: 0 bias; 2 silu; 3 bias+residual(bf16,in-place); 4 split u|gate.
// LNFOLD: A is raw residual x; val = rv*acc - rv*mu*wvec[gn] + bvec[gn] + bias.
// STATS: per-row sum/sumsq of written bf16 into stats_out (pre-zeroed).
// FSCAN (MODE 4 u-half): fused chunk suffix-sum -> clast_out, replacing k_scan_a.
//   chunk g=gm>>4 lies entirely in this block: row-in-chunk = qd*4+r, so
//   clast[g][d] = sum_t dec^(15-t) u_t[d] = qdb(qd) * sum_r fv_r*dec^(3-r),
//   reduced over qd via shfl_xor(16,32); unique writer per (chunk, column).
template<int MODE, bool LNFOLD, bool STATS, bool FSCAN>
__global__ __launch_bounds__(256, 4) void k_gemm128(
    const short* __restrict__ A, const short* __restrict__ Bt,
    const float* __restrict__ bias, const float* __restrict__ bias2,
    const float* __restrict__ wvec, const float* __restrict__ bvec,
    const float* __restrict__ stats_in, float* __restrict__ stats_out,
    u16* __restrict__ res, u16* __restrict__ outp, u16* __restrict__ outp2,
    const float* __restrict__ dlog, float* __restrict__ clast_out,
    int N, int K, int ncol)
{
  __shared__ short As[2][128 * 32];
  __shared__ short Bs[2][128 * 32];
  __shared__ float s_mu[128], s_rv[128];
  const int tid = threadIdx.x;
  const int lane = tid & 63, w = tid >> 6;
  const int wr = w >> 1, wc = w & 1;
  const int l16 = lane & 15, qd = lane >> 4;

  const int b = blockIdx.x;
  const int xcd = b & 7, t = b >> 3;
  const int m0 = (xcd * 16 + t / ncol) * 128;
  const int n0 = (t % ncol) * 128;

  const int sr = lane >> 2, sc = lane & 3;
  const int ar = w * 32 + sr;
  const int acx = sc ^ ((ar >> 1) & 3);
  const short* ag0 = A  + (size_t)(m0 + ar) * K + acx * 8;
  const short* ag1 = ag0 + (size_t)16 * K;
  const short* bg0 = Bt + (size_t)(n0 + ar) * K + acx * 8;
  const short* bg1 = bg0 + (size_t)16 * K;

  auto stg = [&](int bi, int k0) {
    short* a0 = &As[bi][w * 1024];
    glds16(ag0 + k0, a0); glds16(ag1 + k0, a0 + 512);
    short* b0 = &Bs[bi][w * 1024];
    glds16(bg0 + k0, b0); glds16(bg1 + k0, b0 + 512);
  };

  const int fo = (qd ^ ((l16 >> 1) & 3)) * 8 + l16 * 32;

  // LN stats load issued first (oldest VMEM; waits stay counted, no queue drain)
  float sv = 0.f, sq = 0.f;
  if (LNFOLD && tid < 128) {
    sv = stats_in[2 * (m0 + tid)];
    sq = stats_in[2 * (m0 + tid) + 1];
  }

  const int NT = K >> 5;   // K is 256, 768 or 1536 -> NT >= 8
  // prologue: tile 0 only (depth-1)
  stg(0, 0);

  if (LNFOLD && tid < 128) {
    float mu  = sv * (1.0f / (float)D_MOD);
    float var = sq * (1.0f / (float)D_MOD) - mu * mu;
    s_mu[tid] = mu;
    s_rv[tid] = 1.0f / sqrtf(var + EPSV);
  }

  f32x4 acc[4][4];
#pragma unroll
  for (int i = 0; i < 4; i++)
#pragma unroll
    for (int j = 0; j < 4; j++) acc[i][j] = (f32x4){0.f, 0.f, 0.f, 0.f};

  // tile 0 landed, publish to all waves
  asm volatile("s_waitcnt vmcnt(0)" ::: "memory");
  __builtin_amdgcn_s_barrier();

  for (int t2 = 0; t2 < NT; ++t2) {
    const int rd = t2 & 1;
    // stage tile t+1 into the buffer tile t-1 vacated (reads of t-1 completed
    // before the barrier ending iter t-1, which precedes this issue)
    if (t2 + 1 < NT) stg(rd ^ 1, (t2 + 1) * 32);
    const char* ab = (const char*)&As[rd][wr * 2048 + fo];
    const char* bb2 = (const char*)&Bs[rd][wc * 2048 + fo];
    bf16x8 af0 = dsr128(ab, 0),    af1 = dsr128(ab, 1024);
    bf16x8 af2 = dsr128(ab, 2048), af3 = dsr128(ab, 3072);
    bf16x8 bf0 = dsr128(bb2, 0),    bf1 = dsr128(bb2, 1024);
    bf16x8 bf2 = dsr128(bb2, 2048), bf3 = dsr128(bb2, 3072);
    asm volatile("s_waitcnt lgkmcnt(0)" ::: "memory");
    __builtin_amdgcn_sched_barrier(0);
    bf16x8 af[4] = {af0, af1, af2, af3};
    bf16x8 bfr[4] = {bf0, bf1, bf2, bf3};
#pragma unroll
    for (int rt = 0; rt < 4; rt++)
#pragma unroll
      for (int ct = 0; ct < 4; ct++)
        acc[rt][ct] = __builtin_amdgcn_mfma_f32_16x16x32_bf16(af[rt], bfr[ct], acc[rt][ct], 0, 0, 0);
    // tile t+1 must be fully landed before any wave reads it next iter
    asm volatile("s_waitcnt vmcnt(0)" ::: "memory");
    __builtin_amdgcn_s_barrier();
  }

  // ---- epilogue. C/D map col=lane&15, row=(lane>>4)*4+reg ----
  const float* bb = bias;
  u16* op = outp;
  int nofs = 0, Nout = N;
  bool sig = false;
  if (MODE == 4) {
    Nout = N >> 1;
    if (n0 >= Nout) { bb = bias2; op = outp2; nofs = Nout; sig = true; }
  }
  const int gmb = m0 + wr * 64 + qd * 4;
  const int gnb = n0 + wc * 64 + l16;
  float bc[4], wv4[4], bv4[4];
#pragma unroll
  for (int ct = 0; ct < 4; ct++) {
    int gn = gnb + ct * 16;
    bc[ct] = bb[gn - nofs];
    if (LNFOLD) { wv4[ct] = wvec[gn]; bv4[ct] = bvec[gn]; }
  }
  // FSCAN decay powers (u-half only): dec per column, qdb = dec^(12-4*qd)
  float dec1[4], dec2[4], dec3[4], qdb[4];
  if (FSCAN && !sig) {
#pragma unroll
    for (int ct = 0; ct < 4; ct++) {
      int gn = gnb + ct * 16;
      float dv = fsigmoid(dlog[gn]);
      dec1[ct] = dv;
      dec2[ct] = dv * dv;
      dec3[ct] = dec2[ct] * dv;
      float d4 = dec2[ct] * dec2[ct];
      float d8 = d4 * d4, d12 = d8 * d4;
      qdb[ct] = (qd == 0) ? d12 : (qd == 1) ? d8 : (qd == 2) ? d4 : 1.0f;
    }
  }
#pragma unroll
  for (int rt = 0; rt < 4; rt++) {
    float cs[4] = {0.f, 0.f, 0.f, 0.f};
#pragma unroll
    for (int r = 0; r < 4; r++) {
      const int gm = gmb + rt * 16 + r;
      float mu = 0.f, rv = 0.f;
      if (LNFOLD) { mu = s_mu[gm - m0]; rv = s_rv[gm - m0]; }
      float ps = 0.f, ps2 = 0.f;
#pragma unroll
      for (int ct = 0; ct < 4; ct++) {
        int gn = gnb + ct * 16;
        float vv = acc[rt][ct][r];
        if (LNFOLD) vv = rv * vv - rv * mu * wv4[ct] + bv4[ct] + bc[ct];
        else        vv += bc[ct];
        if (MODE == 2) vv = vv * fsigmoid(vv);
        if (MODE == 4 && sig) vv = fsigmoid(vv);
        size_t oidx = (size_t)gm * Nout + (gn - nofs);
        if (MODE == 3) vv += bf2f(res[oidx]);
        u16 rb = f2bf(vv);
        op[oidx] = rb;
        if (STATS) { float fv = bf2f(rb); ps += fv; ps2 += fv * fv; }
        if (FSCAN && !sig) {
          float fv = bf2f(rb);   // stored bf16 value, matching scan input exactly
          float wp = (r == 0) ? dec3[ct] : (r == 1) ? dec2[ct] : (r == 2) ? dec1[ct] : 1.0f;
          cs[ct] = fmaf(fv, wp, cs[ct]);
        }
      }
      if (STATS) {
#pragma unroll
        for (int o = 1; o < 16; o <<= 1) {
          ps  += __shfl_xor(ps, o, 64);
          ps2 += __shfl_xor(ps2, o, 64);
        }
        if (l16 == 0) {
          atomicAdd(&stats_out[2 * gm], ps);
          atomicAdd(&stats_out[2 * gm + 1], ps2);
        }
      }
    }
    if (FSCAN && !sig) {
      const int cidx = (m0 + wr * 64 + rt * 16) >> 4;   // global chunk index
#pragma unroll
      for (int ct = 0; ct < 4; ct++) {
        float c = cs[ct] * qdb[ct];
        c += __shfl_xor(c, 16, 64);
        c += __shfl_xor(c, 32, 64);
        if (qd == 0)
          clast_out[(size_t)cidx * D_MOD + gnb + ct * 16] = c;
      }
    }
  }
}

// ---------------- chunked linear-recurrence scan (u bf16, 4 ch/thread) ----------------
// S_T=16, S_G=1024; clast now produced by the u-GEMM epilogue (FSCAN). Hierarchical
// group-level scan: b1 (32 superblocks x 32 groups) + b2 (32 totals) -- round-10 verified.
// level 1: superblock sb scans its 32 groups (zero entry). inner[g] = carry entering
// group g within sb; sbsum[sb] = chain value after all 32 groups.
__global__ void k_scan_b1(const float* __restrict__ clast, const float* __restrict__ dl,
                          float* __restrict__ inner, float* __restrict__ sbsum) {
  int d = threadIdx.x;            // 0..767
  int sb = blockIdx.x;            // 0..31
  float dec = fsigmoid(dl[d]);
  float aT = dec;
#pragma unroll
  for (int i = 0; i < 4; i++) aT *= aT;   // decay^16
  const float* cp = clast + (size_t)sb * 32 * D_MOD + d;
  float* ip = inner + (size_t)sb * 32 * D_MOD + d;
  float c = 0.f;
#pragma unroll
  for (int j = 0; j < 32; j++) {          // full unroll: loads batch-issue
    ip[(size_t)j * D_MOD] = c;
    c = fmaf(aT, c, cp[(size_t)j * D_MOD]);
  }
  sbsum[(size_t)sb * D_MOD + d] = c;
}

// level 2: scan the 32 superblock totals. multiplier = decay^(16*32) = decay^512.
__global__ void k_scan_b2(const float* __restrict__ sbsum, const float* __restrict__ dl,
                          float* __restrict__ sbcarry) {
  int d = threadIdx.x;            // 0..767
  float dec = fsigmoid(dl[d]);
  float A = dec;
#pragma unroll
  for (int i = 0; i < 9; i++) A *= A;     // decay^512
  float c = 0.f;
#pragma unroll
  for (int sb = 0; sb < 32; sb++) {
    sbcarry[(size_t)sb * D_MOD + d] = c;
    c = fmaf(A, c, sbsum[(size_t)sb * D_MOD + d]);
  }
}

__global__ void k_scan_c(const bf16* __restrict__ u, const float* __restrict__ dl,
                         const float* __restrict__ inner, const float* __restrict__ sbcarry,
                         bf16* __restrict__ gate_s) {
  int t = threadIdx.x;            // 0..191
  int g = blockIdx.x;
  int d0 = t * 4;
  float dec[4], s[4];
#pragma unroll
  for (int c = 0; c < 4; c++) dec[c] = fsigmoid(dl[d0 + c]);
  // carry entering group g = inner[g] + aTg^(g&31) * sbcarry[g>>5]
  {
    float4 iv = *(const float4*)(inner + (size_t)g * D_MOD + d0);
    float4 sv = *(const float4*)(sbcarry + (size_t)(g >> 5) * D_MOD + d0);
    int e = g & 31;                       // block-uniform
    float pw[4], bs[4];
#pragma unroll
    for (int c = 0; c < 4; c++) {
      float aT = dec[c];
#pragma unroll
      for (int i = 0; i < 4; i++) aT *= aT;   // decay^16
      pw[c] = 1.f; bs[c] = aT;
    }
#pragma unroll
    for (int bit = 0; bit < 5; bit++) {
      if ((e >> bit) & 1) {
#pragma unroll
        for (int c = 0; c < 4; c++) pw[c] *= bs[c];
      }
#pragma unroll
      for (int c = 0; c < 4; c++) bs[c] *= bs[c];
    }
    s[0] = fmaf(pw[0], sv.x, iv.x);
    s[1] = fmaf(pw[1], sv.y, iv.y);
    s[2] = fmaf(pw[2], sv.z, iv.z);
    s[3] = fmaf(pw[3], sv.w, iv.w);
  }
  const ushort4* up = (const ushort4*)(u + (size_t)g * S_T * D_MOD) + t;
  ushort4* gp = (ushort4*)(gate_s + (size_t)g * S_T * D_MOD) + t;
  ushort4 nu = up[0], ng = gp[0];
#pragma unroll 4
  for (int tt = 0; tt < S_T; tt++) {
    ushort4 uv = nu, gv = ng;
    if (tt + 1 < S_T) {
      nu = up[(size_t)(tt + 1) * 192];
      ng = gp[(size_t)(tt + 1) * 192];
    }
    s[0] = fmaf(dec[0], s[0], bf2f(uv.x));
    s[1] = fmaf(dec[1], s[1], bf2f(uv.y));
    s[2] = fmaf(dec[2], s[2], bf2f(uv.z));
    s[3] = fmaf(dec[3], s[3], bf2f(uv.w));
    ushort4 ov;
    ov.x = f2bf(s[0] * bf2f(gv.x));
    ov.y = f2bf(s[1] * bf2f(gv.y));
    ov.z = f2bf(s[2] * bf2f(gv.z));
    ov.w = f2bf(s[3] * bf2f(gv.w));
    gp[(size_t)tt * 192] = ov;
  }
}

// ---------------- final LN: x bf16 + precomputed stats -> f32 out ----------------
__global__ __launch_bounds__(256) void k_ln_final(const u16* __restrict__ x,
    const float* __restrict__ stats, const float* __restrict__ g,
    const float* __restrict__ b, float* __restrict__ outp) {
  int wv = threadIdx.x >> 6, lane = threadIdx.x & 63;
  int row = blockIdx.x * 4 + wv;
  float sv = stats[2 * row], sq = stats[2 * row + 1];
  float mu = sv * (1.0f / (float)D_MOD);
  float var = sq * (1.0f / (float)D_MOD) - mu * mu;
  float rv = 1.0f / sqrtf(var + EPSV);
  const ushort4* xr = (const ushort4*)(x + (size_t)row * D_MOD);
  const float4* g4 = (const float4*)g;
  const float4* b4 = (const float4*)b;
  float4* o4 = (float4*)(outp + (size_t)row * D_MOD);
#pragma unroll
  for (int j = 0; j < 3; j++) {
    int f = j * 64 + lane;
    ushort4 xv = xr[f];
    float4 gg = g4[f], bb = b4[f], ov;
    ov.x = (bf2f(xv.x) - mu) * rv * gg.x + bb.x;
    ov.y = (bf2f(xv.y) - mu) * rv * gg.y + bb.y;
    ov.z = (bf2f(xv.z) - mu) * rv * gg.z + bb.z;
    ov.w = (bf2f(xv.w) - mu) * rv * gg.w + bb.w;
    o4[f] = ov;
  }
}

extern "C" void kernel_launch(void* const* d_in, const int* in_sizes, int n_in,
                              void* d_out, int out_size, void* d_ws, size_t ws_size,
                              hipStream_t stream) {
  const float* nf     = (const float*)d_in[0];
  const float* W_proj = (const float*)d_in[1];
  const float* b_proj = (const float*)d_in[2];
  const float* ln_s_g = (const float*)d_in[3];
  const float* ln_s_b = (const float*)d_in[4];
  const float* W_in   = (const float*)d_in[5];
  const float* b_in   = (const float*)d_in[6];
  const float* W_gate = (const float*)d_in[7];
  const float* b_gate = (const float*)d_in[8];
  const float* W_out  = (const float*)d_in[9];
  const float* b_out  = (const float*)d_in[10];
  const float* dlogit = (const float*)d_in[11];
  const float* ln_f_g = (const float*)d_in[12];
  const float* ln_f_b = (const float*)d_in[13];
  const float* W_ff1  = (const float*)d_in[14];
  const float* b_ff1  = (const float*)d_in[15];
  const float* W_ff2  = (const float*)d_in[16];
  const float* b_ff2  = (const float*)d_in[17];
  const float* ln_o_g = (const float*)d_in[18];
  const float* ln_o_b = (const float*)d_in[19];
  (void)in_sizes; (void)n_in;

  char* ws = (char*)d_ws;
  size_t off = 0;
  auto alloc = [&](size_t bytes) -> char* {
    char* p = ws + off;
    off = (off + bytes + 255) & ~(size_t)255;
    return p;
  };
  const bool big = ws_size >= (160ull << 20);
  const size_t wmul = big ? N_LAYER : 1;

  u16*   x     = (u16*)alloc(2ull * L_TOK * D_MOD);        // residual stream, bf16 (25 MB)
  // shared region (50.3 MB): nfb (pre-loop) | u+gate (recurrence) | tb (FF)
  char*  ug    = alloc(2ull * L_TOK * D_FF);
  u16*   u     = (u16*)ug;
  u16*   gate  = (u16*)(ug + 2ull * L_TOK * D_MOD);
  u16*   tb    = (u16*)ug;
  u16*   nfb   = (u16*)ug;
  bf16*  WprojT= (bf16*)alloc(2ull * D_INP * D_MOD);
  bf16*  WigT  = (bf16*)alloc(2ull * wmul * (2 * D_MOD) * D_MOD);  // [g∘W_in^T ; g∘W_gate^T]
  bf16*  WoT   = (bf16*)alloc(2ull * wmul * D_MOD * D_MOD);
  bf16*  Wff1T = (bf16*)alloc(2ull * wmul * D_MOD * D_FF);
  bf16*  Wff2T = (bf16*)alloc(2ull * wmul * D_FF * D_MOD);
  float* clast = (float*)alloc(sizeof(float) * (size_t)S_G * D_MOD);
  float* carry = (float*)alloc(sizeof(float) * (size_t)S_G * D_MOD);   // inner carries
  float* sbsum = (float*)alloc(sizeof(float) * (size_t)S_SB * D_MOD);
  float* sbcar = (float*)alloc(sizeof(float) * (size_t)S_SB * D_MOD);
  // zeroed region: stats slots [17][16384][2] + fold vectors
  char*  zbase = alloc(0);
  float* stats = (float*)alloc(sizeof(float) * 17ull * L_TOK * 2);     // 2.23 MB
  float* wvig  = (float*)alloc(sizeof(float) * N_LAYER * 2 * D_MOD);   // g_s@[W_in|W_gate]
  float* bvig  = (float*)alloc(sizeof(float) * N_LAYER * 2 * D_MOD);
  float* wvf1  = (float*)alloc(sizeof(float) * N_LAYER * D_FF);        // g_f@W_ff1
  float* bvf1  = (float*)alloc(sizeof(float) * N_LAYER * D_FF);
  size_t zbytes = (size_t)((char*)ws + off - zbase);
  hipMemsetAsync(zbase, 0, zbytes, stream);

  const size_t DD = (size_t)D_MOD * D_MOD, DF = (size_t)D_MOD * D_FF;
  auto statslot = [&](int s) { return stats + (size_t)s * L_TOK * 2; };
  dim3 tb32(32, 8);
  k_f32_to_bf16v<<<(L_TOK * D_INP / 4 + 255) / 256, 256, 0, stream>>>(
      (const float4*)nf, (ushort4*)nfb, L_TOK * D_INP / 4);
  k_transpose_fold<false><<<dim3(D_MOD / 32, D_INP / 32, 1), tb32, 0, stream>>>(
      W_proj, WprojT, D_INP, D_MOD, 0, 0, nullptr, nullptr, nullptr, nullptr, 0);
  if (big) {
    k_transpose_fold<true><<<dim3(D_MOD / 32, D_MOD / 32, N_LAYER), tb32, 0, stream>>>(
        W_in,   WigT,      D_MOD, D_MOD, DD, 2 * DD, ln_s_g, ln_s_b, wvig,       bvig,       2 * D_MOD);
    k_transpose_fold<true><<<dim3(D_MOD / 32, D_MOD / 32, N_LAYER), tb32, 0, stream>>>(
        W_gate, WigT + DD, D_MOD, D_MOD, DD, 2 * DD, ln_s_g, ln_s_b, wvig + D_MOD, bvig + D_MOD, 2 * D_MOD);
    k_transpose_fold<false><<<dim3(D_MOD / 32, D_MOD / 32, N_LAYER), tb32, 0, stream>>>(
        W_out,  WoT,       D_MOD, D_MOD, DD, DD, nullptr, nullptr, nullptr, nullptr, 0);
    k_transpose_fold<true><<<dim3(D_FF / 32,  D_MOD / 32, N_LAYER), tb32, 0, stream>>>(
        W_ff1,  Wff1T,     D_MOD, D_FF,  DF, DF, ln_f_g, ln_f_b, wvf1, bvf1, D_FF);
    k_transpose_fold<false><<<dim3(D_MOD / 32, D_FF / 32,  N_LAYER), tb32, 0, stream>>>(
        W_ff2,  Wff2T,     D_FF,  D_MOD, DF, DF, nullptr, nullptr, nullptr, nullptr, 0);
  }

  // x = nf @ W_proj + b_proj  (bf16 out + stats slot 0)
  k_gemm128<0, false, true, false><<<128 * 6, 256, 0, stream>>>(
      (const short*)nfb, (const short*)WprojT, b_proj, nullptr, nullptr, nullptr,
      nullptr, statslot(0), nullptr, x, nullptr, nullptr, nullptr, D_MOD, D_INP, 6);

  for (int l = 0; l < N_LAYER; l++) {
    const bf16 *wigT, *woT, *wf1T, *wf2T;
    if (big) {
      wigT = WigT  + (size_t)l * 2 * DD;
      woT  = WoT   + (size_t)l * DD;
      wf1T = Wff1T + (size_t)l * DF;
      wf2T = Wff2T + (size_t)l * DF;
    } else {
      k_transpose_fold<true><<<dim3(D_MOD / 32, D_MOD / 32, 1), tb32, 0, stream>>>(
          W_in + (size_t)l * DD, WigT, D_MOD, D_MOD, 0, 0,
          ln_s_g + l * D_MOD, ln_s_b + l * D_MOD, wvig + (size_t)l * 2 * D_MOD, bvig + (size_t)l * 2 * D_MOD, 0);
      k_transpose_fold<true><<<dim3(D_MOD / 32, D_MOD / 32, 1), tb32, 0, stream>>>(
          W_gate + (size_t)l * DD, WigT + DD, D_MOD, D_MOD, 0, 0,
          ln_s_g + l * D_MOD, ln_s_b + l * D_MOD, wvig + (size_t)l * 2 * D_MOD + D_MOD, bvig + (size_t)l * 2 * D_MOD + D_MOD, 0);
      k_transpose_fold<false><<<dim3(D_MOD / 32, D_MOD / 32, 1), tb32, 0, stream>>>(
          W_out + (size_t)l * DD, WoT, D_MOD, D_MOD, 0, 0, nullptr, nullptr, nullptr, nullptr, 0);
      k_transpose_fold<true><<<dim3(D_FF / 32, D_MOD / 32, 1), tb32, 0, stream>>>(
          W_ff1 + (size_t)l * DF, Wff1T, D_MOD, D_FF, 0, 0,
          ln_f_g + l * D_MOD, ln_f_b + l * D_MOD, wvf1 + (size_t)l * D_FF, bvf1 + (size_t)l * D_FF, 0);
      k_transpose_fold<false><<<dim3(D_MOD / 32, D_FF / 32, 1), tb32, 0, stream>>>(
          W_ff2 + (size_t)l * DF, Wff2T, D_FF, D_MOD, 0, 0, nullptr, nullptr, nullptr, nullptr, 0);
      wigT = WigT; woT = WoT; wf1T = Wff1T; wf2T = Wff2T;
    }

    // fused LN_s + (u | gate) GEMM + chunk suffix-sums (clast): A = x directly
    k_gemm128<4, true, false, true><<<128 * 12, 256, 0, stream>>>(
        (const short*)x, (const short*)wigT, b_in + l * D_MOD, b_gate + l * D_MOD,
        wvig + (size_t)l * 2 * D_MOD, bvig + (size_t)l * 2 * D_MOD,
        statslot(2 * l), nullptr, nullptr, u, gate,
        dlogit + l * D_MOD, clast, 2 * D_MOD, D_MOD, 12);
    // hierarchical group-level scan; s*gate -> gate buffer (bf16)
    k_scan_b1<<<S_G / 32, D_MOD, 0, stream>>>(clast, dlogit + l * D_MOD, carry, sbsum);
    k_scan_b2<<<1, D_MOD, 0, stream>>>(sbsum, dlogit + l * D_MOD, sbcar);
    k_scan_c<<<S_G, 192, 0, stream>>>((const bf16*)u, dlogit + l * D_MOD, carry, sbcar, (bf16*)gate);
    // x = x + sg @ W_out + b_out  (bf16 in-place + stats slot 2l+1)
    k_gemm128<3, false, true, false><<<128 * 6, 256, 0, stream>>>(
        (const short*)gate, (const short*)woT, b_out + l * D_MOD, nullptr, nullptr, nullptr,
        nullptr, statslot(2 * l + 1), x, x, nullptr, nullptr, nullptr, D_MOD, D_MOD, 6);
    // fused LN_f + FF1 (silu): A = x directly
    k_gemm128<2, true, false, false><<<128 * 12, 256, 0, stream>>>(
        (const short*)x, (const short*)wf1T, b_ff1 + l * D_FF, nullptr,
        wvf1 + (size_t)l * D_FF, bvf1 + (size_t)l * D_FF,
        statslot(2 * l + 1), nullptr, nullptr, tb, nullptr, nullptr, nullptr, D_FF, D_MOD, 12);
    // x = x + tb @ W_ff2 + b_ff2  (bf16 in-place + stats slot 2l+2)
    k_gemm128<3, false, true, false><<<128 * 6, 256, 0, stream>>>(
        (const short*)tb, (const short*)wf2T, b_ff2 + l * D_MOD, nullptr, nullptr, nullptr,
        nullptr, statslot(2 * l + 2), x, x, nullptr, nullptr, nullptr, D_MOD, D_FF, 6);
  }

  // out = LN_o(x) (f32) using stats slot 16
  k_ln_final<<<L_TOK / 4, 256, 0, stream>>>(x, statslot(2 * N_LAYER), ln_o_g, ln_o_b, (float*)d_out);
}